// Round 1
// baseline (5157.117 us; speedup 1.0000x reference)
//
#include <hip/hip_runtime.h>
#include <math.h>

// ---------------------------------------------------------------------------
// PD_Block fp32 baseline.
// Key facts derived from the reference:
//  * v_w / v_b (7x7 conv) are DEAD: vh is never consumed, split branch == 0.
//  * Live heavy compute: conv5x5 x2 (53.6 G-MAC each), proj 1x1 (2.1 G-MAC).
//  * Cluster: per s in [0,64): M=4 centers, N=4096 points, c=32 channels.
// Buffers: A, B in ws; y lives in d_out (final kernel reads y then overwrites
// elementwise, which is safe).
// ---------------------------------------------------------------------------

#define NT   8388608ull        // 2*256*128*128
#define CHW  4194304           // 256*128*128
#define HW   16384             // 128*128

// ---------------------------------------------------------------- zero stats
__global__ void zero_stats_k(float* __restrict__ stats) {
    stats[threadIdx.x] = 0.f;
}

// ------------------------------------------------- generic group-stat reduce
// Groups are contiguous memory runs (true for GN1 per-batch and GN16).
__global__ __launch_bounds__(256) void reduce_stats_k(
    const float* __restrict__ src, float* __restrict__ stats,
    int elems_per_group, int blocks_per_group)
{
    int g   = blockIdx.x / blocks_per_group;
    int blk = blockIdx.x % blocks_per_group;
    int per_block = elems_per_group / blocks_per_group;
    const float* p = src + (size_t)g * elems_per_group + (size_t)blk * per_block;
    float s = 0.f, ss = 0.f;
    for (int i = threadIdx.x * 4; i < per_block; i += 256 * 4) {
        float4 v = *(const float4*)(p + i);
        s  += (v.x + v.y) + (v.z + v.w);
        ss += (v.x * v.x + v.y * v.y) + (v.z * v.z + v.w * v.w);
    }
    // wave reduce
    for (int off = 32; off; off >>= 1) {
        s  += __shfl_down(s, off);
        ss += __shfl_down(ss, off);
    }
    __shared__ float rs[4], rss[4];
    int lane = threadIdx.x & 63, wv = threadIdx.x >> 6;
    if (lane == 0) { rs[wv] = s; rss[wv] = ss; }
    __syncthreads();
    if (threadIdx.x == 0) {
        float a = rs[0] + rs[1] + rs[2] + rs[3];
        float b = rss[0] + rss[1] + rss[2] + rss[3];
        atomicAdd(&stats[2 * g],     a);
        atomicAdd(&stats[2 * g + 1], b);
    }
}

// ------------------------------------------------------------- GN apply(+silu)
__global__ __launch_bounds__(256) void gn_apply_k(
    const float* __restrict__ src, float* __restrict__ dst,
    const float* __restrict__ stats, const float* __restrict__ gw,
    const float* __restrict__ gb, int ch_per_group, float inv_n, int do_silu)
{
    size_t i = ((size_t)blockIdx.x * 256 + threadIdx.x) * 4;
    float4 v = *(const float4*)(src + i);
    int ch    = (int)((i >> 14) & 255);
    int batch = (int)(i >> 22);
    int g = batch * (256 / ch_per_group) + ch / ch_per_group;
    float mean = stats[2 * g] * inv_n;
    float var  = stats[2 * g + 1] * inv_n - mean * mean;
    float rsv  = rsqrtf(var + 1e-5f);
    float sc = rsv * gw[ch];
    float sh = gb[ch] - mean * sc;
    float o[4] = { v.x * sc + sh, v.y * sc + sh, v.z * sc + sh, v.w * sc + sh };
    if (do_silu) {
        #pragma unroll
        for (int k = 0; k < 4; k++) o[k] = o[k] / (1.f + expf(-o[k]));
    }
    float4 r; r.x = o[0]; r.y = o[1]; r.z = o[2]; r.w = o[3];
    *(float4*)(dst + i) = r;
}

// ------------------------------------------------------- cluster: centers cf
// blockIdx.x = s*4 + m ; s = ((bb*8+head)*2+f2)*2+f3 ; m = mw*2+mh
__global__ __launch_bounds__(256) void centers_k(
    const float* __restrict__ A, float* __restrict__ cf)
{
    int sm = blockIdx.x;
    int m = sm & 3, s = sm >> 2;
    int f3 = s & 1, f2 = (s >> 1) & 1, head = (s >> 2) & 7, bb = s >> 5;
    int mh = m & 1, mw = m >> 1;
    int c = threadIdx.x & 31, grp = threadIdx.x >> 5;     // 8 row groups
    const float* base = A + ((size_t)(bb * 256 + head * 32 + c) * 128
                             + f2 * 64 + mw * 32) * 128 + f3 * 64 + mh * 32;
    float sum = 0.f;
    for (int r = grp; r < 32; r += 8) {
        const float* row = base + r * 128;
        #pragma unroll
        for (int q = 0; q < 8; q++) {
            float4 v = *(const float4*)(row + q * 4);
            sum += (v.x + v.y) + (v.z + v.w);
        }
    }
    __shared__ float red[8][32];
    red[grp][c] = sum;
    __syncthreads();
    if (grp == 0) {
        float t = 0.f;
        #pragma unroll
        for (int k = 0; k < 8; k++) t += red[k][c];
        cf[(size_t)sm * 32 + c] = t * (1.f / 1024.f);
    }
}

// ----------------------------------- cluster: sim + dense_out (one block per s)
__global__ __launch_bounds__(256, 1) void sim_dense_k(
    const float* __restrict__ A, const float* __restrict__ cf,
    float* __restrict__ simb, float* __restrict__ dense,
    const float* __restrict__ alphap, const float* __restrict__ betap)
{
    int s = blockIdx.x;
    int f3 = s & 1, f2 = (s >> 1) & 1, head = (s >> 2) & 7, bb = s >> 5;
    int tid = threadIdx.x;
    float alpha = alphap[0], beta = betap[0];

    __shared__ float cfr[4][32], cfn[4][32], invn[4];
    if (tid < 128) {
        int m = tid >> 5, c = tid & 31;
        cfr[m][c] = cf[(size_t)(s * 4 + m) * 32 + c];
    }
    __syncthreads();
    if (tid < 4) {
        float n = 0.f;
        for (int c = 0; c < 32; c++) n += cfr[tid][c] * cfr[tid][c];
        invn[tid] = 1.f / fmaxf(sqrtf(n), 1e-12f);
    }
    __syncthreads();
    if (tid < 128) {
        int m = tid >> 5, c = tid & 31;
        cfn[m][c] = cfr[m][c] * invn[m];
    }
    __syncthreads();

    const float* xbase = A + ((size_t)(bb * 256 + head * 32) * 128 + f2 * 64) * 128
                           + f3 * 64;
    float num[4][32];
    float den[4] = {0.f, 0.f, 0.f, 0.f};
    #pragma unroll
    for (int m = 0; m < 4; m++)
        #pragma unroll
        for (int c = 0; c < 32; c++) num[m][c] = 0.f;

    for (int n0 = 0; n0 < 4096; n0 += 256) {
        int n = n0 + tid;
        int w = n >> 6, h = n & 63;
        const float* px = xbase + w * 128 + h;
        float f[32]; float ss = 0.f;
        #pragma unroll
        for (int c = 0; c < 32; c++) { f[c] = px[(size_t)c * HW]; ss += f[c] * f[c]; }
        float inv = 1.f / fmaxf(sqrtf(ss), 1e-12f);
        #pragma unroll
        for (int m = 0; m < 4; m++) {
            float dot = 0.f;
            #pragma unroll
            for (int c = 0; c < 32; c++) dot += cfn[m][c] * f[c];
            float z = beta + alpha * dot * inv;
            float sv = 1.f / (1.f + expf(-z));
            simb[((size_t)s * 4 + m) * 4096 + n] = sv;
            den[m] += sv;
            #pragma unroll
            for (int c = 0; c < 32; c++) num[m][c] = fmaf(sv, f[c], num[m][c]);
        }
    }

    // reduce 256 threads -> totals
    __shared__ float rnum[4][128];
    __shared__ float rden[4][4];
    __shared__ float dfin[4];
    int lane = tid & 63, wv = tid >> 6;
    #pragma unroll
    for (int m = 0; m < 4; m++) {
        #pragma unroll
        for (int c = 0; c < 32; c++) {
            float v = num[m][c];
            for (int off = 32; off; off >>= 1) v += __shfl_xor(v, off);
            if (lane == 0) rnum[wv][m * 32 + c] = v;
        }
        float d = den[m];
        for (int off = 32; off; off >>= 1) d += __shfl_xor(d, off);
        if (lane == 0) rden[wv][m] = d;
    }
    __syncthreads();
    if (tid < 4) dfin[tid] = rden[0][tid] + rden[1][tid] + rden[2][tid] + rden[3][tid];
    __syncthreads();
    if (tid < 128) {
        int m = tid >> 5, c = tid & 31;
        float nsum = rnum[0][tid] + rnum[1][tid] + rnum[2][tid] + rnum[3][tid];
        dense[(size_t)(s * 4 + m) * 32 + c] = (nsum + cfr[m][c]) / (dfin[m] + 1.0f);
    }
}

// ----------------------------------------- cluster: dispatch back to points
// grid = 64 s * 16 chunks ; out[c][n] = sum_m dense[m][c]*sim[m][n]
__global__ __launch_bounds__(256) void dispatch_k(
    const float* __restrict__ simb, const float* __restrict__ dense,
    float* __restrict__ B)
{
    int s = blockIdx.x >> 4, chunk = blockIdx.x & 15;
    int tid = threadIdx.x;
    __shared__ float dl[4][32];
    if (tid < 128) {
        int m = tid >> 5, c = tid & 31;
        dl[m][c] = dense[(size_t)(s * 4 + m) * 32 + c];
    }
    __syncthreads();
    int n = chunk * 256 + tid;
    int w = n >> 6, h = n & 63;
    int f3 = s & 1, f2 = (s >> 1) & 1, head = (s >> 2) & 7, bb = s >> 5;
    float sv[4];
    #pragma unroll
    for (int m = 0; m < 4; m++) sv[m] = simb[((size_t)s * 4 + m) * 4096 + n];
    float* ob = B + ((size_t)(bb * 256 + head * 32) * 128 + f2 * 64 + w) * 128
                  + f3 * 64 + h;
    #pragma unroll
    for (int c = 0; c < 32; c++) {
        ob[(size_t)c * HW] = dl[0][c] * sv[0] + dl[1][c] * sv[1]
                           + dl[2][c] * sv[2] + dl[3][c] * sv[3];
    }
}

// ----------------------------------------------------- weight transposes
// w [co][ci][25] -> wT [ci][25][co]
__global__ __launch_bounds__(256) void transpose_w5_k(
    const float* __restrict__ w, float* __restrict__ wT)
{
    int ci = blockIdx.x >> 2, co0 = (blockIdx.x & 3) * 64;
    __shared__ float tile[64 * 25];
    for (int idx = threadIdx.x; idx < 1600; idx += 256) {
        int co = idx / 25, k = idx % 25;
        tile[idx] = w[((size_t)(co0 + co) * 256 + ci) * 25 + k];
    }
    __syncthreads();
    for (int idx = threadIdx.x; idx < 1600; idx += 256) {
        int co = idx & 63, k = idx >> 6;
        wT[((size_t)ci * 25 + k) * 256 + co0 + co] = tile[co * 25 + k];
    }
}

// proj w [co][ci] -> wT [ci][co]
__global__ void transpose_proj_k(const float* __restrict__ w, float* __restrict__ wT) {
    int ci = blockIdx.x, co = threadIdx.x;
    wT[(size_t)ci * 256 + co] = w[(size_t)co * 256 + ci];
}

// ----------------------------------------------------- 1x1 conv + silu
// block: 256 co x 32 px ; grid = 2 b * 512 px-chunks
__global__ __launch_bounds__(256) void proj_k(
    const float* __restrict__ src, const float* __restrict__ wT,
    const float* __restrict__ bias, float* __restrict__ dst)
{
    int bb = blockIdx.x >> 9, pxc = blockIdx.x & 511;
    size_t pix0 = (size_t)pxc * 32;
    int tid = threadIdx.x;
    int co = tid;
    __shared__ __align__(16) float in_s[64][32];
    __shared__ float outs[256 * 33];
    float acc[32];
    #pragma unroll
    for (int p = 0; p < 32; p++) acc[p] = 0.f;

    for (int ci0 = 0; ci0 < 256; ci0 += 64) {
        __syncthreads();
        {
            int lci = tid >> 2, lp = (tid & 3) * 8;
            const float* sp = src + ((size_t)(bb * 256 + ci0 + lci)) * HW + pix0 + lp;
            float4 v0 = *(const float4*)(sp);
            float4 v1 = *(const float4*)(sp + 4);
            *(float4*)&in_s[lci][lp]     = v0;
            *(float4*)&in_s[lci][lp + 4] = v1;
        }
        __syncthreads();
        for (int ci = 0; ci < 64; ci++) {
            float wv = wT[(size_t)(ci0 + ci) * 256 + co];
            #pragma unroll
            for (int p4 = 0; p4 < 8; p4++) {
                float4 iv = *(const float4*)&in_s[ci][p4 * 4];
                acc[p4 * 4 + 0] = fmaf(wv, iv.x, acc[p4 * 4 + 0]);
                acc[p4 * 4 + 1] = fmaf(wv, iv.y, acc[p4 * 4 + 1]);
                acc[p4 * 4 + 2] = fmaf(wv, iv.z, acc[p4 * 4 + 2]);
                acc[p4 * 4 + 3] = fmaf(wv, iv.w, acc[p4 * 4 + 3]);
            }
        }
    }
    float bv = bias[co];
    #pragma unroll
    for (int p = 0; p < 32; p++) outs[co * 33 + p] = acc[p] + bv;
    __syncthreads();
    for (int idx = tid; idx < 8192; idx += 256) {
        int px = idx & 31, c = idx >> 5;
        float v = outs[c * 33 + px];
        v = v / (1.f + expf(-v));
        dst[((size_t)(bb * 256 + c)) * HW + pix0 + px] = v;
    }
}

// ----------------------------------------------------- y = x + alpha*mix
__global__ __launch_bounds__(256) void add_scale_k(
    const float* __restrict__ x, const float* __restrict__ mix,
    const float* __restrict__ alphap, float* __restrict__ dst)
{
    size_t i = ((size_t)blockIdx.x * 256 + threadIdx.x) * 4;
    float a = alphap[0];
    float4 vx = *(const float4*)(x + i);
    float4 vm = *(const float4*)(mix + i);
    float4 r;
    r.x = vx.x + a * vm.x; r.y = vx.y + a * vm.y;
    r.z = vx.z + a * vm.z; r.w = vx.w + a * vm.w;
    *(float4*)(dst + i) = r;
}

// ----------------------------------------------------- 5x5 conv (pad 2)
// block tile: 64 co x 128 px (one output row), thread tile 4 co x 8 px.
// grid: blockIdx.x = ((bb*4 + cot)*128 + y) -> 1024 blocks.
// wT layout: [ci][25][co]. addbuf: optional residual (elementwise, may alias dst).
__global__ __launch_bounds__(256) void conv5x5_k(
    const float* __restrict__ src, const float* __restrict__ wT,
    const float* __restrict__ bias, const float* __restrict__ addbuf,
    float* __restrict__ dst)
{
    int y   = blockIdx.x & 127;
    int cot = (blockIdx.x >> 7) & 3;
    int bb  = blockIdx.x >> 9;
    int co0 = cot * 64;
    int tid = threadIdx.x;
    int cog = tid & 15;      // 16 groups of 4 co
    int pxg = tid >> 4;      // 16 groups of 8 px
    int px0 = pxg * 8;

    __shared__ __align__(16) float wlds[8 * 25 * 64];    // [ci][k][64co]
    __shared__ __align__(16) float ilds[8 * 5 * 136];    // [ci][ky][136]

    float acc[4][8];
    #pragma unroll
    for (int a = 0; a < 4; a++)
        #pragma unroll
        for (int b = 0; b < 8; b++) acc[a][b] = 0.f;

    for (int ci0 = 0; ci0 < 256; ci0 += 8) {
        __syncthreads();
        // stage weights (coalesced: 64-consecutive co per row)
        for (int idx = tid; idx < 8 * 25 * 64; idx += 256) {
            int co = idx & 63, rest = idx >> 6;          // rest = ci*25+k
            wlds[idx] = wT[(size_t)(ci0 * 25 + rest) * 256 + co0 + co];
        }
        // stage input rows y-2..y+2 with x halo, zero-padded
        for (int idx = tid; idx < 8 * 5 * 136; idx += 256) {
            int p = idx % 136, row = idx / 136;
            int ky = row % 5, ci = row / 5;
            int x = p - 2, iy = y + ky - 2;
            float v = 0.f;
            if (p < 132 && (unsigned)x < 128u && (unsigned)iy < 128u)
                v = src[(((size_t)(bb * 256 + ci0 + ci)) * 128 + iy) * 128 + x];
            ilds[idx] = v;
        }
        __syncthreads();
        #pragma unroll
        for (int ci = 0; ci < 8; ci++) {
            #pragma unroll
            for (int ky = 0; ky < 5; ky++) {
                const float* ir = &ilds[(ci * 5 + ky) * 136 + px0];
                float in[12];
                {
                    float4 a4 = *(const float4*)(ir);
                    float4 b4 = *(const float4*)(ir + 4);
                    float4 c4 = *(const float4*)(ir + 8);
                    in[0] = a4.x; in[1] = a4.y; in[2]  = a4.z; in[3]  = a4.w;
                    in[4] = b4.x; in[5] = b4.y; in[6]  = b4.z; in[7]  = b4.w;
                    in[8] = c4.x; in[9] = c4.y; in[10] = c4.z; in[11] = c4.w;
                }
                const float* wr = &wlds[(ci * 25 + ky * 5) * 64 + cog * 4];
                #pragma unroll
                for (int kx = 0; kx < 5; kx++) {
                    float4 wv = *(const float4*)(wr + kx * 64);
                    float wa[4] = { wv.x, wv.y, wv.z, wv.w };
                    #pragma unroll
                    for (int co = 0; co < 4; co++)
                        #pragma unroll
                        for (int px = 0; px < 8; px++)
                            acc[co][px] = fmaf(wa[co], in[px + kx], acc[co][px]);
                }
            }
        }
    }
    // epilogue
    #pragma unroll
    for (int co = 0; co < 4; co++) {
        int c = co0 + cog * 4 + co;
        float bv = bias[c];
        size_t ob = (((size_t)(bb * 256 + c)) * 128 + y) * 128 + px0;
        float o[8];
        #pragma unroll
        for (int px = 0; px < 8; px++) o[px] = acc[co][px] + bv;
        if (addbuf) {
            #pragma unroll
            for (int px = 0; px < 8; px++) o[px] += addbuf[ob + px];
        }
        float4 r0, r1;
        r0.x = o[0]; r0.y = o[1]; r0.z = o[2]; r0.w = o[3];
        r1.x = o[4]; r1.y = o[5]; r1.z = o[6]; r1.w = o[7];
        *(float4*)(dst + ob)     = r0;
        *(float4*)(dst + ob + 4) = r1;
    }
}

// ---------------------------------------------------------------------------
extern "C" void kernel_launch(void* const* d_in, const int* in_sizes, int n_in,
                              void* d_out, int out_size, void* d_ws, size_t ws_size,
                              hipStream_t stream)
{
    (void)in_sizes; (void)n_in; (void)out_size; (void)ws_size;
    const float* x        = (const float*)d_in[0];
    const float* norm1_w  = (const float*)d_in[1];
    const float* norm1_b  = (const float*)d_in[2];
    // d_in[3] (v_w), d_in[4] (v_b): dead code in the reference — skipped.
    const float* proj_w   = (const float*)d_in[5];
    const float* proj_b   = (const float*)d_in[6];
    const float* cn_w     = (const float*)d_in[7];
    const float* cn_b     = (const float*)d_in[8];
    const float* sim_a    = (const float*)d_in[9];
    const float* sim_b    = (const float*)d_in[10];
    const float* con_a    = (const float*)d_in[11];
    const float* rn1_w    = (const float*)d_in[12];
    const float* rn1_b    = (const float*)d_in[13];
    const float* rc1_w    = (const float*)d_in[14];
    const float* rc1_b    = (const float*)d_in[15];
    const float* rn2_w    = (const float*)d_in[16];
    const float* rn2_b    = (const float*)d_in[17];
    const float* rc2_w    = (const float*)d_in[18];
    const float* rc2_b    = (const float*)d_in[19];

    float* ws = (float*)d_ws;
    float* A    = ws;                 // [2,256,128,128]
    float* Bb   = ws + NT;            // [2,256,128,128]
    size_t o = 2ull * NT;
    float* cf    = ws + o; o += 8192;       // [64,4,32]
    float* dense = ws + o; o += 8192;       // [64,4,32]
    float* simb  = ws + o; o += 1048576;    // [64,4,4096]
    float* wT1   = ws + o; o += 1638400;    // rc1 transposed [ci][25][co]
    float* wT2   = ws + o; o += 1638400;
    float* wTp   = ws + o; o += 65536;      // proj transposed [ci][co]
    float* stats = ws + o; o += 256;        // gn1a@0, gn1b@4, gn16a@8, gn16b@72
    float* C = (float*)d_out;               // y buffer aliases the output

    zero_stats_k<<<1, 256, 0, stream>>>(stats);
    transpose_w5_k<<<1024, 256, 0, stream>>>(rc1_w, wT1);
    transpose_w5_k<<<1024, 256, 0, stream>>>(rc2_w, wT2);
    transpose_proj_k<<<256, 256, 0, stream>>>(proj_w, wTp);

    // xg = GN1(x)
    reduce_stats_k<<<2048, 256, 0, stream>>>(x, stats + 0, CHW, 1024);
    gn_apply_k<<<8192, 256, 0, stream>>>(x, A, stats + 0, norm1_w, norm1_b,
                                         256, 1.f / CHW, 0);
    // cluster
    centers_k<<<256, 256, 0, stream>>>(A, cf);
    sim_dense_k<<<64, 256, 0, stream>>>(A, cf, simb, dense, sim_a, sim_b);
    dispatch_k<<<1024, 256, 0, stream>>>(simb, dense, Bb);
    // GN1 (cn) in place, then proj 1x1 + silu -> A (mix)
    reduce_stats_k<<<2048, 256, 0, stream>>>(Bb, stats + 4, CHW, 1024);
    gn_apply_k<<<8192, 256, 0, stream>>>(Bb, Bb, stats + 4, cn_w, cn_b,
                                         256, 1.f / CHW, 0);
    proj_k<<<1024, 256, 0, stream>>>(Bb, wTp, proj_b, A);
    // y = x + alpha*mix  (stored in d_out)
    add_scale_k<<<8192, 256, 0, stream>>>(x, A, con_a, C);
    // ResnetBlock
    reduce_stats_k<<<256, 256, 0, stream>>>(C, stats + 8, 262144, 8);
    gn_apply_k<<<8192, 256, 0, stream>>>(C, A, stats + 8, rn1_w, rn1_b,
                                         16, 1.f / 262144, 1);
    conv5x5_k<<<1024, 256, 0, stream>>>(A, wT1, rc1_b, nullptr, Bb);
    reduce_stats_k<<<256, 256, 0, stream>>>(Bb, stats + 72, 262144, 8);
    gn_apply_k<<<8192, 256, 0, stream>>>(Bb, A, stats + 72, rn2_w, rn2_b,
                                         16, 1.f / 262144, 1);
    conv5x5_k<<<1024, 256, 0, stream>>>(A, wT2, rc2_b, C, C);
}

// Round 3
// 1058.878 us; speedup vs baseline: 4.8704x; 4.8704x over previous
//
#include <hip/hip_runtime.h>
#include <math.h>

// ---------------------------------------------------------------------------
// PD_Block, round 2 (resubmit — R2 bench never ran: GPU acquisition timeout).
// conv5x5 -> split-bf16 MFMA implicit GEMM.
//  * x,w each split hi+lo bf16; 3 MFMA terms (hh, hl, lh) -> fp32-level accuracy.
//  * A operand (activations) pre-transposed to channel-last, split, XOR-swizzled
//    (u' = u ^ (xslot&7), 16B units) padded global buffer XtG[b][cib][ys134][xs134][64]
//    so conv staging is linear global_load_lds (wave-uniform dest + lane*16).
//  * W pre-split to [cib][ky][kx][co][64k] rows with same swizzle (u' = u ^ (co&7)).
//  * conv block: 4 output rows x 64 co, 4 waves (wave = 1 row x 64 co,
//    8 px-frags x 4 co-frags, acc 128 VGPR). Sliding 4-row LDS ring per ky.
// ---------------------------------------------------------------------------

#define NT   8388608ull        // 2*256*128*128
#define CHW  4194304           // 256*128*128
#define HW   16384             // 128*128

typedef unsigned short u16;
typedef __attribute__((ext_vector_type(8))) short bf16x8;
typedef __attribute__((ext_vector_type(4))) float f32x4;

#define MFMA16(a,b,c) __builtin_amdgcn_mfma_f32_16x16x32_bf16(a,b,c,0,0,0)

__device__ __forceinline__ u16 f2bf(float f) {
    unsigned u = __float_as_uint(f);
    unsigned r = (u + 0x7fffu + ((u >> 16) & 1u)) >> 16;
    return (u16)r;
}
__device__ __forceinline__ float bf2f(u16 h) {
    return __uint_as_float((unsigned)h << 16);
}

__device__ __forceinline__ void gll16(const void* g, void* l) {
    __builtin_amdgcn_global_load_lds(
        (const __attribute__((address_space(1))) void*)g,
        (__attribute__((address_space(3))) void*)l, 16, 0, 0);
}
// linear global->LDS copy; 4 waves cooperate; bytes may overrun up to +512
// into LDS (callers provide slack) and reads stay inside the global buffer.
__device__ __forceinline__ void stage_lin(const char* g, char* l, int bytes) {
    int lane = threadIdx.x & 63, wv = threadIdx.x >> 6;
    for (int off = wv << 10; off < bytes; off += 4096)
        gll16(g + off + lane * 16, l + off);
}

// ---------------------------------------------------------------- zero stats
__global__ void zero_stats_k(float* __restrict__ stats) {
    stats[threadIdx.x] = 0.f;
}
__global__ __launch_bounds__(256) void zero_buf_k(uint4* __restrict__ p, int n) {
    for (int i = blockIdx.x * 256 + threadIdx.x; i < n; i += 2048 * 256)
        p[i] = make_uint4(0u, 0u, 0u, 0u);
}

// ------------------------------------------------- generic group-stat reduce
__global__ __launch_bounds__(256) void reduce_stats_k(
    const float* __restrict__ src, float* __restrict__ stats,
    int elems_per_group, int blocks_per_group)
{
    int g   = blockIdx.x / blocks_per_group;
    int blk = blockIdx.x % blocks_per_group;
    int per_block = elems_per_group / blocks_per_group;
    const float* p = src + (size_t)g * elems_per_group + (size_t)blk * per_block;
    float s = 0.f, ss = 0.f;
    for (int i = threadIdx.x * 4; i < per_block; i += 256 * 4) {
        float4 v = *(const float4*)(p + i);
        s  += (v.x + v.y) + (v.z + v.w);
        ss += (v.x * v.x + v.y * v.y) + (v.z * v.z + v.w * v.w);
    }
    for (int off = 32; off; off >>= 1) {
        s  += __shfl_down(s, off);
        ss += __shfl_down(ss, off);
    }
    __shared__ float rs[4], rss[4];
    int lane = threadIdx.x & 63, wv = threadIdx.x >> 6;
    if (lane == 0) { rs[wv] = s; rss[wv] = ss; }
    __syncthreads();
    if (threadIdx.x == 0) {
        float a = rs[0] + rs[1] + rs[2] + rs[3];
        float b = rss[0] + rss[1] + rss[2] + rss[3];
        atomicAdd(&stats[2 * g],     a);
        atomicAdd(&stats[2 * g + 1], b);
    }
}

// ------------------------------------------------------------- GN apply
__global__ __launch_bounds__(256) void gn_apply_k(
    const float* __restrict__ src, float* __restrict__ dst,
    const float* __restrict__ stats, const float* __restrict__ gw,
    const float* __restrict__ gb, int ch_per_group, float inv_n, int do_silu)
{
    size_t i = ((size_t)blockIdx.x * 256 + threadIdx.x) * 4;
    float4 v = *(const float4*)(src + i);
    int ch    = (int)((i >> 14) & 255);
    int batch = (int)(i >> 22);
    int g = batch * (256 / ch_per_group) + ch / ch_per_group;
    float mean = stats[2 * g] * inv_n;
    float var  = stats[2 * g + 1] * inv_n - mean * mean;
    float rsv  = rsqrtf(var + 1e-5f);
    float sc = rsv * gw[ch];
    float sh = gb[ch] - mean * sc;
    float o[4] = { v.x * sc + sh, v.y * sc + sh, v.z * sc + sh, v.w * sc + sh };
    if (do_silu) {
        #pragma unroll
        for (int k = 0; k < 4; k++) o[k] = o[k] / (1.f + expf(-o[k]));
    }
    float4 r; r.x = o[0]; r.y = o[1]; r.z = o[2]; r.w = o[3];
    *(float4*)(dst + i) = r;
}

// ------------------------------------------------------- cluster: centers cf
__global__ __launch_bounds__(256) void centers_k(
    const float* __restrict__ A, float* __restrict__ cf)
{
    int sm = blockIdx.x;
    int m = sm & 3, s = sm >> 2;
    int f3 = s & 1, f2 = (s >> 1) & 1, head = (s >> 2) & 7, bb = s >> 5;
    int mh = m & 1, mw = m >> 1;
    int c = threadIdx.x & 31, grp = threadIdx.x >> 5;
    const float* base = A + ((size_t)(bb * 256 + head * 32 + c) * 128
                             + f2 * 64 + mw * 32) * 128 + f3 * 64 + mh * 32;
    float sum = 0.f;
    for (int r = grp; r < 32; r += 8) {
        const float* row = base + r * 128;
        #pragma unroll
        for (int q = 0; q < 8; q++) {
            float4 v = *(const float4*)(row + q * 4);
            sum += (v.x + v.y) + (v.z + v.w);
        }
    }
    __shared__ float red[8][32];
    red[grp][c] = sum;
    __syncthreads();
    if (grp == 0) {
        float t = 0.f;
        #pragma unroll
        for (int k = 0; k < 8; k++) t += red[k][c];
        cf[(size_t)sm * 32 + c] = t * (1.f / 1024.f);
    }
}

// ----------------------------------- cluster: sim + dense_out
__global__ __launch_bounds__(256, 1) void sim_dense_k(
    const float* __restrict__ A, const float* __restrict__ cf,
    float* __restrict__ simb, float* __restrict__ dense,
    const float* __restrict__ alphap, const float* __restrict__ betap)
{
    int s = blockIdx.x;
    int f3 = s & 1, f2 = (s >> 1) & 1, head = (s >> 2) & 7, bb = s >> 5;
    int tid = threadIdx.x;
    float alpha = alphap[0], beta = betap[0];

    __shared__ float cfr[4][32], cfn[4][32], invn[4];
    if (tid < 128) {
        int m = tid >> 5, c = tid & 31;
        cfr[m][c] = cf[(size_t)(s * 4 + m) * 32 + c];
    }
    __syncthreads();
    if (tid < 4) {
        float n = 0.f;
        for (int c = 0; c < 32; c++) n += cfr[tid][c] * cfr[tid][c];
        invn[tid] = 1.f / fmaxf(sqrtf(n), 1e-12f);
    }
    __syncthreads();
    if (tid < 128) {
        int m = tid >> 5, c = tid & 31;
        cfn[m][c] = cfr[m][c] * invn[m];
    }
    __syncthreads();

    const float* xbase = A + ((size_t)(bb * 256 + head * 32) * 128 + f2 * 64) * 128
                           + f3 * 64;
    float num[4][32];
    float den[4] = {0.f, 0.f, 0.f, 0.f};
    #pragma unroll
    for (int m = 0; m < 4; m++)
        #pragma unroll
        for (int c = 0; c < 32; c++) num[m][c] = 0.f;

    for (int n0 = 0; n0 < 4096; n0 += 256) {
        int n = n0 + tid;
        int w = n >> 6, h = n & 63;
        const float* px = xbase + w * 128 + h;
        float f[32]; float ss = 0.f;
        #pragma unroll
        for (int c = 0; c < 32; c++) { f[c] = px[(size_t)c * HW]; ss += f[c] * f[c]; }
        float inv = 1.f / fmaxf(sqrtf(ss), 1e-12f);
        #pragma unroll
        for (int m = 0; m < 4; m++) {
            float dot = 0.f;
            #pragma unroll
            for (int c = 0; c < 32; c++) dot += cfn[m][c] * f[c];
            float z = beta + alpha * dot * inv;
            float sv = 1.f / (1.f + expf(-z));
            simb[((size_t)s * 4 + m) * 4096 + n] = sv;
            den[m] += sv;
            #pragma unroll
            for (int c = 0; c < 32; c++) num[m][c] = fmaf(sv, f[c], num[m][c]);
        }
    }

    __shared__ float rnum[4][128];
    __shared__ float rden[4][4];
    __shared__ float dfin[4];
    int lane = tid & 63, wv = tid >> 6;
    #pragma unroll
    for (int m = 0; m < 4; m++) {
        #pragma unroll
        for (int c = 0; c < 32; c++) {
            float v = num[m][c];
            for (int off = 32; off; off >>= 1) v += __shfl_xor(v, off);
            if (lane == 0) rnum[wv][m * 32 + c] = v;
        }
        float d = den[m];
        for (int off = 32; off; off >>= 1) d += __shfl_xor(d, off);
        if (lane == 0) rden[wv][m] = d;
    }
    __syncthreads();
    if (tid < 4) dfin[tid] = rden[0][tid] + rden[1][tid] + rden[2][tid] + rden[3][tid];
    __syncthreads();
    if (tid < 128) {
        int m = tid >> 5, c = tid & 31;
        float nsum = rnum[0][tid] + rnum[1][tid] + rnum[2][tid] + rnum[3][tid];
        dense[(size_t)(s * 4 + m) * 32 + c] = (nsum + cfr[m][c]) / (dfin[m] + 1.0f);
    }
}

// ----------------------------------------- cluster: dispatch back to points
__global__ __launch_bounds__(256) void dispatch_k(
    const float* __restrict__ simb, const float* __restrict__ dense,
    float* __restrict__ B)
{
    int s = blockIdx.x >> 4, chunk = blockIdx.x & 15;
    int tid = threadIdx.x;
    __shared__ float dl[4][32];
    if (tid < 128) {
        int m = tid >> 5, c = tid & 31;
        dl[m][c] = dense[(size_t)(s * 4 + m) * 32 + c];
    }
    __syncthreads();
    int n = chunk * 256 + tid;
    int w = n >> 6, h = n & 63;
    int f3 = s & 1, f2 = (s >> 1) & 1, head = (s >> 2) & 7, bb = s >> 5;
    float sv[4];
    #pragma unroll
    for (int m = 0; m < 4; m++) sv[m] = simb[((size_t)s * 4 + m) * 4096 + n];
    float* ob = B + ((size_t)(bb * 256 + head * 32) * 128 + f2 * 64 + w) * 128
                  + f3 * 64 + h;
    #pragma unroll
    for (int c = 0; c < 32; c++) {
        ob[(size_t)c * HW] = dl[0][c] * sv[0] + dl[1][c] * sv[1]
                           + dl[2][c] * sv[2] + dl[3][c] * sv[3];
    }
}

// proj w [co][ci] -> wT [ci][co]
__global__ void transpose_proj_k(const float* __restrict__ w, float* __restrict__ wT) {
    int ci = blockIdx.x, co = threadIdx.x;
    wT[(size_t)ci * 256 + co] = w[(size_t)co * 256 + ci];
}

// ----------------------------------------------------- 1x1 conv + silu
__global__ __launch_bounds__(256) void proj_k(
    const float* __restrict__ src, const float* __restrict__ wT,
    const float* __restrict__ bias, float* __restrict__ dst)
{
    int bb = blockIdx.x >> 9, pxc = blockIdx.x & 511;
    size_t pix0 = (size_t)pxc * 32;
    int tid = threadIdx.x;
    int co = tid;
    __shared__ __align__(16) float in_s[64][32];
    __shared__ float outs[256 * 33];
    float acc[32];
    #pragma unroll
    for (int p = 0; p < 32; p++) acc[p] = 0.f;

    for (int ci0 = 0; ci0 < 256; ci0 += 64) {
        __syncthreads();
        {
            int lci = tid >> 2, lp = (tid & 3) * 8;
            const float* sp = src + ((size_t)(bb * 256 + ci0 + lci)) * HW + pix0 + lp;
            float4 v0 = *(const float4*)(sp);
            float4 v1 = *(const float4*)(sp + 4);
            *(float4*)&in_s[lci][lp]     = v0;
            *(float4*)&in_s[lci][lp + 4] = v1;
        }
        __syncthreads();
        for (int ci = 0; ci < 64; ci++) {
            float wv = wT[(size_t)(ci0 + ci) * 256 + co];
            #pragma unroll
            for (int p4 = 0; p4 < 8; p4++) {
                float4 iv = *(const float4*)&in_s[ci][p4 * 4];
                acc[p4 * 4 + 0] = fmaf(wv, iv.x, acc[p4 * 4 + 0]);
                acc[p4 * 4 + 1] = fmaf(wv, iv.y, acc[p4 * 4 + 1]);
                acc[p4 * 4 + 2] = fmaf(wv, iv.z, acc[p4 * 4 + 2]);
                acc[p4 * 4 + 3] = fmaf(wv, iv.w, acc[p4 * 4 + 3]);
            }
        }
    }
    float bv = bias[co];
    #pragma unroll
    for (int p = 0; p < 32; p++) outs[co * 33 + p] = acc[p] + bv;
    __syncthreads();
    for (int idx = tid; idx < 8192; idx += 256) {
        int px = idx & 31, c = idx >> 5;
        float v = outs[c * 33 + px];
        v = v / (1.f + expf(-v));
        dst[((size_t)(bb * 256 + c)) * HW + pix0 + px] = v;
    }
}

// ----------------------------------------------------- y = x + alpha*mix
__global__ __launch_bounds__(256) void add_scale_k(
    const float* __restrict__ x, const float* __restrict__ mix,
    const float* __restrict__ alphap, float* __restrict__ dst)
{
    size_t i = ((size_t)blockIdx.x * 256 + threadIdx.x) * 4;
    float a = alphap[0];
    float4 vx = *(const float4*)(x + i);
    float4 vm = *(const float4*)(mix + i);
    float4 r;
    r.x = vx.x + a * vm.x; r.y = vx.y + a * vm.y;
    r.z = vx.z + a * vm.z; r.w = vx.w + a * vm.w;
    *(float4*)(dst + i) = r;
}

// ------------------------------------------------ prep: weights -> split bf16
// rc_w fp32 [co][ci][5][5] -> Ws[cib][ky][kx][co][64k] bf16; k-row = hi(32)|lo(32),
// stored in 16B units at swizzled position u' = u ^ (co&7).
// one thread per 16B unit; grid 1600 x 256 = 409600 units exactly.
__global__ __launch_bounds__(256) void prep_w_k(
    const float* __restrict__ w, u16* __restrict__ Ws)
{
    int idx = blockIdx.x * 256 + threadIdx.x;
    int up = idx & 7; int t = idx >> 3;
    int co = t & 255; t >>= 8;
    int kx = t % 5; t /= 5;
    int ky = t % 5; t /= 5;
    int cib = t;
    int u = up ^ (co & 7);
    int lo = (u >= 4);
    int ci0 = cib * 32 + (u & 3) * 8;
    u16 vals[8];
    #pragma unroll
    for (int j = 0; j < 8; ++j) {
        float wv = w[(((size_t)co * 256 + (ci0 + j)) * 5 + ky) * 5 + kx];
        u16 h = f2bf(wv);
        vals[j] = lo ? f2bf(wv - bf2f(h)) : h;
    }
    uint4 v;
    v.x = (unsigned)vals[0] | ((unsigned)vals[1] << 16);
    v.y = (unsigned)vals[2] | ((unsigned)vals[3] << 16);
    v.z = (unsigned)vals[4] | ((unsigned)vals[5] << 16);
    v.w = (unsigned)vals[6] | ((unsigned)vals[7] << 16);
    *(uint4*)(Ws + (size_t)idx * 8) = v;
}

// -------------------- prep: GN16 + silu + split + transpose -> XtG (padded)
// src fp32 NCHW -> XtG[b][cib][ys=y+2][xs=x+2][64] bf16, row = hi(32)|lo(32),
// 16B units stored at u' = u ^ (xs&7). grid = 2b*128y, 256 thr.
__global__ __launch_bounds__(256) void prep_xtg_k(
    const float* __restrict__ src, const float* __restrict__ stats,
    const float* __restrict__ gw, const float* __restrict__ gb,
    u16* __restrict__ XtG)
{
    int bb = blockIdx.x >> 7, yy = blockIdx.x & 127;
    __shared__ float tile[256][33];
    int tid = threadIdx.x;
    int xx = tid & 31, cg = tid >> 5;          // cg == cib
    for (int xc = 0; xc < 4; ++xc) {
        int x0 = xc * 32;
        __syncthreads();
        for (int i = tid; i < 8192; i += 256) {
            int c = i >> 5, xl = i & 31;
            tile[c][xl] = src[((size_t)(bb * 256 + c) * 128 + yy) * 128 + x0 + xl];
        }
        __syncthreads();
        int x = x0 + xx;
        u16 vals[64];
        #pragma unroll
        for (int ci = 0; ci < 32; ++ci) {
            int c = cg * 32 + ci;
            int g = bb * 16 + (c >> 4);
            float mean = stats[2 * g] * (1.f / 262144.f);
            float var  = stats[2 * g + 1] * (1.f / 262144.f) - mean * mean;
            float rsv  = rsqrtf(var + 1e-5f);
            float v = (tile[c][xx] - mean) * rsv * gw[c] + gb[c];
            v = v / (1.f + expf(-v));
            u16 h = f2bf(v);
            float lo = v - bf2f(h);
            vals[(ci >> 3) * 8 + (ci & 7)]      = h;
            vals[32 + (ci >> 3) * 8 + (ci & 7)] = f2bf(lo);
        }
        int s = (x + 2) & 7;
        u16* base = XtG + ((((size_t)bb * 8 + cg) * 134 + (yy + 2)) * 134 + (x + 2)) * 64;
        #pragma unroll
        for (int u = 0; u < 8; ++u) {
            uint4 v;
            v.x = (unsigned)vals[u*8+0] | ((unsigned)vals[u*8+1] << 16);
            v.y = (unsigned)vals[u*8+2] | ((unsigned)vals[u*8+3] << 16);
            v.z = (unsigned)vals[u*8+4] | ((unsigned)vals[u*8+5] << 16);
            v.w = (unsigned)vals[u*8+6] | ((unsigned)vals[u*8+7] << 16);
            *(uint4*)(base + (u ^ s) * 8) = v;
        }
    }
}

// --------------------------------------- conv5x5 via split-bf16 MFMA GEMM
// block: 4 output rows (y0..y0+3) x 64 co; 4 waves; wave = 1 row x 64 co.
// acc: 8 px-frags x 4 co-frags of 16x16. K loop: cib(8) x ky(5) x kx(5) x 3 terms.
// Abuf: sliding ring of 4 input rows (xslot = x+2, 64 k-elems/row, swizzled).
__global__ __launch_bounds__(256, 1) void conv_mfma_k(
    const u16* __restrict__ XtG, const u16* __restrict__ Ws,
    const float* __restrict__ bias, const float* __restrict__ addbuf,
    float* __restrict__ dst)
{
    __shared__ u16 Abuf[4][136][64];   // 69632 B (136: +4 rows staging slack)
    __shared__ u16 Wlds[5][64][64];    // 40960 B

    int bid = blockIdx.x;
    int b   = bid >> 7;
    int y4  = (bid >> 2) & 31;
    int coq = bid & 3;
    int y0  = y4 * 4;
    int co0 = coq * 64;
    int tid  = threadIdx.x;
    int lane = tid & 63, wv = tid >> 6;
    int l15 = lane & 15, lg = lane >> 4;
    int y = y0 + wv;

    f32x4 acc[8][4];
    #pragma unroll
    for (int m = 0; m < 8; ++m)
        #pragma unroll
        for (int nf = 0; nf < 4; ++nf)
            acc[m][nf] = (f32x4){0.f, 0.f, 0.f, 0.f};

    for (int cib = 0; cib < 8; ++cib) {
        const u16* Xc = XtG + ((size_t)(b * 8 + cib)) * 134 * 134 * 64;
        // stage rows r = y0-2 .. y0+1  (ys = y0 .. y0+3), slot = r&3
        #pragma unroll
        for (int rr = 0; rr < 4; ++rr) {
            int ys = y0 + rr;
            stage_lin((const char*)(Xc + (size_t)ys * 134 * 64),
                      (char*)&Abuf[(ys - 2) & 3][0][0], 132 * 128);
        }
        for (int ky = 0; ky < 5; ++ky) {
            if (ky > 0) {
                int r = y0 + ky + 1;
                stage_lin((const char*)(Xc + (size_t)(r + 2) * 134 * 64),
                          (char*)&Abuf[r & 3][0][0], 132 * 128);
            }
            const u16* Wt = Ws + ((((size_t)cib * 5 + ky) * 5) * 256 + co0) * 64;
            #pragma unroll
            for (int kx = 0; kx < 5; ++kx)
                stage_lin((const char*)(Wt + (size_t)kx * 256 * 64),
                          (char*)&Wlds[kx][0][0], 64 * 128);
            __syncthreads();

            const u16* Ab = &Abuf[(y + ky - 2) & 3][0][0];
            #pragma unroll
            for (int kx = 0; kx < 5; ++kx) {
                const u16* Wk = &Wlds[kx][0][0];
                bf16x8 bh[4], bl[4], ah[8];
                #pragma unroll
                for (int nf = 0; nf < 4; ++nf) {
                    int cr = nf * 16 + l15;
                    int ph = lg ^ (cr & 7);
                    const u16* wp = Wk + cr * 64;
                    bh[nf] = *(const bf16x8*)(wp + ph * 8);
                    bl[nf] = *(const bf16x8*)(wp + (ph ^ 4) * 8);
                }
                #pragma unroll
                for (int m = 0; m < 8; ++m) {
                    int xs = m * 16 + l15 + kx;
                    ah[m] = *(const bf16x8*)(Ab + xs * 64 + (lg ^ (xs & 7)) * 8);
                }
                #pragma unroll
                for (int m = 0; m < 8; ++m)
                    #pragma unroll
                    for (int nf = 0; nf < 4; ++nf)
                        acc[m][nf] = MFMA16(ah[m], bh[nf], acc[m][nf]);
                #pragma unroll
                for (int m = 0; m < 8; ++m)
                    #pragma unroll
                    for (int nf = 0; nf < 4; ++nf)
                        acc[m][nf] = MFMA16(ah[m], bl[nf], acc[m][nf]);
                #pragma unroll
                for (int m = 0; m < 8; ++m) {
                    int xs = m * 16 + l15 + kx;
                    ah[m] = *(const bf16x8*)(Ab + xs * 64 + ((lg ^ (xs & 7)) ^ 4) * 8);
                }
                #pragma unroll
                for (int m = 0; m < 8; ++m)
                    #pragma unroll
                    for (int nf = 0; nf < 4; ++nf)
                        acc[m][nf] = MFMA16(ah[m], bh[nf], acc[m][nf]);
            }
            __syncthreads();
        }
    }

    // epilogue: D row (px) = m*16 + lg*4 + reg ; D col (co) = co0 + nf*16 + l15
    #pragma unroll
    for (int nf = 0; nf < 4; ++nf) {
        int co = co0 + nf * 16 + l15;
        float bv = bias[co];
        size_t rowb = ((size_t)(b * 256 + co) * 128 + y) * 128;
        #pragma unroll
        for (int m = 0; m < 8; ++m) {
            size_t ob = rowb + m * 16 + lg * 4;
            f32x4 v = acc[m][nf];
            v.x += bv; v.y += bv; v.z += bv; v.w += bv;
            if (addbuf) {
                float4 r = *(const float4*)(addbuf + ob);
                v.x += r.x; v.y += r.y; v.z += r.z; v.w += r.w;
            }
            *(f32x4*)(dst + ob) = v;
        }
    }
}

// ---------------------------------------------------------------------------
extern "C" void kernel_launch(void* const* d_in, const int* in_sizes, int n_in,
                              void* d_out, int out_size, void* d_ws, size_t ws_size,
                              hipStream_t stream)
{
    (void)in_sizes; (void)n_in; (void)out_size; (void)ws_size;
    const float* x        = (const float*)d_in[0];
    const float* norm1_w  = (const float*)d_in[1];
    const float* norm1_b  = (const float*)d_in[2];
    // d_in[3] (v_w), d_in[4] (v_b): dead code in the reference — skipped.
    const float* proj_w   = (const float*)d_in[5];
    const float* proj_b   = (const float*)d_in[6];
    const float* cn_w     = (const float*)d_in[7];
    const float* cn_b     = (const float*)d_in[8];
    const float* sim_a    = (const float*)d_in[9];
    const float* sim_b    = (const float*)d_in[10];
    const float* con_a    = (const float*)d_in[11];
    const float* rn1_w    = (const float*)d_in[12];
    const float* rn1_b    = (const float*)d_in[13];
    const float* rc1_w    = (const float*)d_in[14];
    const float* rc1_b    = (const float*)d_in[15];
    const float* rn2_w    = (const float*)d_in[16];
    const float* rn2_b    = (const float*)d_in[17];
    const float* rc2_w    = (const float*)d_in[18];
    const float* rc2_b    = (const float*)d_in[19];

    float* ws = (float*)d_ws;
    float* A    = ws;                       // [2,256,128,128] fp32
    float* Bb   = ws + NT;                  // [2,256,128,128] fp32
    size_t o = 2ull * NT;
    float* cf    = ws + o; o += 8192;
    float* dense = ws + o; o += 8192;
    float* simb  = ws + o; o += 1048576;
    float* wTp   = ws + o; o += 65536;
    float* stats = ws + o; o += 256;        // gn1a@0, gn1b@4, gn16a@8, gn16b@72
    u16* XtG = (u16*)(ws + o);              // 2*8*134*134*64 = 18,384,896 u16
    const size_t XTG_ELEMS = 2ull * 8 * 134 * 134 * 64;
    u16* Ws1 = XtG + XTG_ELEMS + 2048;      // 25*8*256*64 = 3,276,800 u16
    u16* Ws2 = Ws1 + 3276800 + 2048;
    float* C = (float*)d_out;               // y buffer aliases the output

    zero_stats_k<<<1, 256, 0, stream>>>(stats);
    zero_buf_k<<<2048, 256, 0, stream>>>((uint4*)XtG, (int)(XTG_ELEMS / 8));
    prep_w_k<<<1600, 256, 0, stream>>>(rc1_w, Ws1);
    prep_w_k<<<1600, 256, 0, stream>>>(rc2_w, Ws2);
    transpose_proj_k<<<256, 256, 0, stream>>>(proj_w, wTp);

    // xg = GN1(x)
    reduce_stats_k<<<2048, 256, 0, stream>>>(x, stats + 0, CHW, 1024);
    gn_apply_k<<<8192, 256, 0, stream>>>(x, A, stats + 0, norm1_w, norm1_b,
                                         256, 1.f / CHW, 0);
    // cluster
    centers_k<<<256, 256, 0, stream>>>(A, cf);
    sim_dense_k<<<64, 256, 0, stream>>>(A, cf, simb, dense, sim_a, sim_b);
    dispatch_k<<<1024, 256, 0, stream>>>(simb, dense, Bb);
    // GN1 (cn), proj 1x1 + silu -> A (mix)
    reduce_stats_k<<<2048, 256, 0, stream>>>(Bb, stats + 4, CHW, 1024);
    gn_apply_k<<<8192, 256, 0, stream>>>(Bb, Bb, stats + 4, cn_w, cn_b,
                                         256, 1.f / CHW, 0);
    proj_k<<<1024, 256, 0, stream>>>(Bb, wTp, proj_b, A);
    // y = x + alpha*mix  (stored in d_out)
    add_scale_k<<<8192, 256, 0, stream>>>(x, A, con_a, C);
    // ResnetBlock conv1
    reduce_stats_k<<<256, 256, 0, stream>>>(C, stats + 8, 262144, 8);
    prep_xtg_k<<<256, 256, 0, stream>>>(C, stats + 8, rn1_w, rn1_b, XtG);
    conv_mfma_k<<<256, 256, 0, stream>>>(XtG, Ws1, rc1_b, nullptr, Bb);
    // ResnetBlock conv2 + residual
    reduce_stats_k<<<256, 256, 0, stream>>>(Bb, stats + 72, 262144, 8);
    prep_xtg_k<<<256, 256, 0, stream>>>(Bb, stats + 72, rn2_w, rn2_b, XtG);
    conv_mfma_k<<<256, 256, 0, stream>>>(XtG, Ws2, rc2_b, C, C);
}

// Round 4
// 1048.044 us; speedup vs baseline: 4.9207x; 1.0103x over previous
//
#include <hip/hip_runtime.h>
#include <math.h>

// ---------------------------------------------------------------------------
// PD_Block, round 4.
//  * conv5x5 split-bf16 MFMA implicit GEMM, now 2-phase pipelined:
//      - W read DIRECTLY from global (L2) — no W LDS staging, no per-step drain.
//      - A ring of 8 row-slots (139 KB LDS); prefetch next step's row(s) before
//        compute; single raw s_barrier + vmcnt(0) per step (stage hides under
//        compute). XCD-swizzled bid: each XCD owns one (coq,b) -> W set 1.6MB<L2.
//  * Elementwise chain fused: GN1 folded into centers/sim (affine), dispatch
//    accumulates Bb stats, proj applies GN-cn inline + silu + residual, conv1
//    epilogue accumulates GN16 stats of t. sim split into 256 blocks w/ atomics.
// ---------------------------------------------------------------------------

#define NT   8388608ull        // 2*256*128*128
#define CHW  4194304           // 256*128*128
#define HW   16384             // 128*128

typedef unsigned short u16;
typedef __attribute__((ext_vector_type(8))) short bf16x8;
typedef __attribute__((ext_vector_type(4))) float f32x4;

#define MFMA16(a,b,c) __builtin_amdgcn_mfma_f32_16x16x32_bf16(a,b,c,0,0,0)

__device__ __forceinline__ u16 f2bf(float f) {
    unsigned u = __float_as_uint(f);
    unsigned r = (u + 0x7fffu + ((u >> 16) & 1u)) >> 16;
    return (u16)r;
}
__device__ __forceinline__ float bf2f(u16 h) {
    return __uint_as_float((unsigned)h << 16);
}

__device__ __forceinline__ void gll16(const void* g, void* l) {
    __builtin_amdgcn_global_load_lds(
        (const __attribute__((address_space(1))) void*)g,
        (__attribute__((address_space(3))) void*)l, 16, 0, 0);
}
// linear global->LDS copy; 4 waves cooperate; may overrun up to +512 B into
// the LDS slot (slots sized for it) and reads stay inside the global buffer.
__device__ __forceinline__ void stage_lin(const char* g, char* l, int bytes) {
    int lane = threadIdx.x & 63, wv = threadIdx.x >> 6;
    for (int off = wv << 10; off < bytes; off += 4096)
        gll16(g + off + lane * 16, l + off);
}

// ---------------------------------------------------------------- zero utils
__global__ void zero_small_k(float* __restrict__ p) {
    p[blockIdx.x * 256 + threadIdx.x] = 0.f;     // grid*256 == region size
}
__global__ __launch_bounds__(256) void zero_buf_k(uint4* __restrict__ p, int n) {
    for (int i = blockIdx.x * 256 + threadIdx.x; i < n; i += 2048 * 256)
        p[i] = make_uint4(0u, 0u, 0u, 0u);
}

// ------------------------------------------------- generic group-stat reduce
__global__ __launch_bounds__(256) void reduce_stats_k(
    const float* __restrict__ src, float* __restrict__ stats,
    int elems_per_group, int blocks_per_group)
{
    int g   = blockIdx.x / blocks_per_group;
    int blk = blockIdx.x % blocks_per_group;
    int per_block = elems_per_group / blocks_per_group;
    const float* p = src + (size_t)g * elems_per_group + (size_t)blk * per_block;
    float s = 0.f, ss = 0.f;
    for (int i = threadIdx.x * 4; i < per_block; i += 256 * 4) {
        float4 v = *(const float4*)(p + i);
        s  += (v.x + v.y) + (v.z + v.w);
        ss += (v.x * v.x + v.y * v.y) + (v.z * v.z + v.w * v.w);
    }
    for (int off = 32; off; off >>= 1) {
        s  += __shfl_down(s, off);
        ss += __shfl_down(ss, off);
    }
    __shared__ float rs[4], rss[4];
    int lane = threadIdx.x & 63, wv = threadIdx.x >> 6;
    if (lane == 0) { rs[wv] = s; rss[wv] = ss; }
    __syncthreads();
    if (threadIdx.x == 0) {
        atomicAdd(&stats[2 * g],     rs[0] + rs[1] + rs[2] + rs[3]);
        atomicAdd(&stats[2 * g + 1], rss[0] + rss[1] + rss[2] + rss[3]);
    }
}

// --------------------------- cluster: centers (pool raw x, then GN1 affine)
__global__ __launch_bounds__(256) void centers_k(
    const float* __restrict__ x, const float* __restrict__ stats,
    const float* __restrict__ n1w, const float* __restrict__ n1b,
    float* __restrict__ cf)
{
    int sm = blockIdx.x;
    int m = sm & 3, s = sm >> 2;
    int f3 = s & 1, f2 = (s >> 1) & 1, head = (s >> 2) & 7, bb = s >> 5;
    int mh = m & 1, mw = m >> 1;
    int c = threadIdx.x & 31, grp = threadIdx.x >> 5;
    const float* base = x + ((size_t)(bb * 256 + head * 32 + c) * 128
                             + f2 * 64 + mw * 32) * 128 + f3 * 64 + mh * 32;
    float sum = 0.f;
    for (int r = grp; r < 32; r += 8) {
        const float* row = base + r * 128;
        #pragma unroll
        for (int q = 0; q < 8; q++) {
            float4 v = *(const float4*)(row + q * 4);
            sum += (v.x + v.y) + (v.z + v.w);
        }
    }
    __shared__ float red[8][32];
    red[grp][c] = sum;
    __syncthreads();
    if (grp == 0) {
        float t = 0.f;
        #pragma unroll
        for (int k = 0; k < 8; k++) t += red[k][c];
        float mean = stats[2 * bb] * (1.f / CHW);
        float var  = stats[2 * bb + 1] * (1.f / CHW) - mean * mean;
        float rsv  = rsqrtf(var + 1e-5f);
        int ch = head * 32 + c;
        float sc = rsv * n1w[ch];
        float sh = n1b[ch] - mean * sc;
        cf[(size_t)sm * 32 + c] = (t * (1.f / 1024.f)) * sc + sh;
    }
}

// --------------- cluster: sim + partial num/den (4 blocks per s, atomics)
__global__ __launch_bounds__(256) void sim_part_k(
    const float* __restrict__ x, const float* __restrict__ stats,
    const float* __restrict__ n1w, const float* __restrict__ n1b,
    const float* __restrict__ cf, float* __restrict__ simb,
    float* __restrict__ nump, float* __restrict__ denp,
    const float* __restrict__ alphap, const float* __restrict__ betap)
{
    int sq = blockIdx.x;
    int q = sq & 3, s = sq >> 2;
    int f3 = s & 1, f2 = (s >> 1) & 1, head = (s >> 2) & 7, bb = s >> 5;
    int tid = threadIdx.x;
    float alpha = alphap[0], beta = betap[0];

    __shared__ float cfr[4][32], cfn[4][32], invn[4], scs[32], shs[32];
    if (tid < 128) {
        int m = tid >> 5, c = tid & 31;
        cfr[m][c] = cf[(size_t)(s * 4 + m) * 32 + c];
    }
    if (tid >= 128 && tid < 160) {
        int c = tid - 128;
        float mean = stats[2 * bb] * (1.f / CHW);
        float var  = stats[2 * bb + 1] * (1.f / CHW) - mean * mean;
        float rsv  = rsqrtf(var + 1e-5f);
        int ch = head * 32 + c;
        float sc = rsv * n1w[ch];
        scs[c] = sc;
        shs[c] = n1b[ch] - mean * sc;
    }
    __syncthreads();
    if (tid < 4) {
        float n = 0.f;
        for (int c = 0; c < 32; c++) n += cfr[tid][c] * cfr[tid][c];
        invn[tid] = 1.f / fmaxf(sqrtf(n), 1e-12f);
    }
    __syncthreads();
    if (tid < 128) {
        int m = tid >> 5, c = tid & 31;
        cfn[m][c] = cfr[m][c] * invn[m];
    }
    __syncthreads();

    const float* xbase = x + ((size_t)(bb * 256 + head * 32) * 128 + f2 * 64) * 128
                           + f3 * 64;
    float num[4][32];
    float den[4] = {0.f, 0.f, 0.f, 0.f};
    #pragma unroll
    for (int m = 0; m < 4; m++)
        #pragma unroll
        for (int c = 0; c < 32; c++) num[m][c] = 0.f;

    for (int n0 = 0; n0 < 1024; n0 += 256) {
        int n = q * 1024 + n0 + tid;
        int w = n >> 6, h = n & 63;
        const float* px = xbase + w * 128 + h;
        float f[32]; float ss = 0.f;
        #pragma unroll
        for (int c = 0; c < 32; c++) {
            f[c] = px[(size_t)c * HW] * scs[c] + shs[c];
            ss += f[c] * f[c];
        }
        float inv = 1.f / fmaxf(sqrtf(ss), 1e-12f);
        #pragma unroll
        for (int m = 0; m < 4; m++) {
            float dot = 0.f;
            #pragma unroll
            for (int c = 0; c < 32; c++) dot += cfn[m][c] * f[c];
            float z = beta + alpha * dot * inv;
            float sv = 1.f / (1.f + expf(-z));
            simb[((size_t)s * 4 + m) * 4096 + n] = sv;
            den[m] += sv;
            #pragma unroll
            for (int c = 0; c < 32; c++) num[m][c] = fmaf(sv, f[c], num[m][c]);
        }
    }

    __shared__ float rnum[4][128];
    __shared__ float rden[4][4];
    int lane = tid & 63, wv = tid >> 6;
    #pragma unroll
    for (int m = 0; m < 4; m++) {
        #pragma unroll
        for (int c = 0; c < 32; c++) {
            float v = num[m][c];
            for (int off = 32; off; off >>= 1) v += __shfl_xor(v, off);
            if (lane == 0) rnum[wv][m * 32 + c] = v;
        }
        float d = den[m];
        for (int off = 32; off; off >>= 1) d += __shfl_xor(d, off);
        if (lane == 0) rden[wv][m] = d;
    }
    __syncthreads();
    if (tid < 4)
        atomicAdd(&denp[s * 4 + tid],
                  rden[0][tid] + rden[1][tid] + rden[2][tid] + rden[3][tid]);
    if (tid < 128) {
        int m = tid >> 5, c = tid & 31;
        float nsum = rnum[0][tid] + rnum[1][tid] + rnum[2][tid] + rnum[3][tid];
        atomicAdd(&nump[(size_t)(s * 4 + m) * 32 + c], nsum);
    }
}

// ------------------------------------------------------- finalize dense_out
__global__ void finalize_dense_k(const float* __restrict__ nump,
                                 const float* __restrict__ denp,
                                 const float* __restrict__ cf,
                                 float* __restrict__ dense)
{
    int i = blockIdx.x * 256 + threadIdx.x;   // 32 blocks * 256 = 8192
    dense[i] = (nump[i] + cf[i]) / (denp[i >> 5] + 1.0f);
}

// ------------- cluster: dispatch back to points (+ fused Bb GN1 stats)
__global__ __launch_bounds__(256) void dispatch_k(
    const float* __restrict__ simb, const float* __restrict__ dense,
    float* __restrict__ B, float* __restrict__ stats)
{
    int s = blockIdx.x >> 4, chunk = blockIdx.x & 15;
    int tid = threadIdx.x;
    __shared__ float dl[4][32];
    if (tid < 128) {
        int m = tid >> 5, c = tid & 31;
        dl[m][c] = dense[(size_t)(s * 4 + m) * 32 + c];
    }
    __syncthreads();
    int n = chunk * 256 + tid;
    int w = n >> 6, h = n & 63;
    int f3 = s & 1, f2 = (s >> 1) & 1, head = (s >> 2) & 7, bb = s >> 5;
    float sv[4];
    #pragma unroll
    for (int m = 0; m < 4; m++) sv[m] = simb[((size_t)s * 4 + m) * 4096 + n];
    float* ob = B + ((size_t)(bb * 256 + head * 32) * 128 + f2 * 64 + w) * 128
                  + f3 * 64 + h;
    float s1 = 0.f, s2 = 0.f;
    #pragma unroll
    for (int c = 0; c < 32; c++) {
        float v = dl[0][c] * sv[0] + dl[1][c] * sv[1]
                + dl[2][c] * sv[2] + dl[3][c] * sv[3];
        ob[(size_t)c * HW] = v;
        s1 += v; s2 += v * v;
    }
    for (int off = 32; off; off >>= 1) {
        s1 += __shfl_xor(s1, off);
        s2 += __shfl_xor(s2, off);
    }
    __shared__ float r1[4], r2[4];
    int lane = tid & 63, wv = tid >> 6;
    if (lane == 0) { r1[wv] = s1; r2[wv] = s2; }
    __syncthreads();
    if (tid == 0) {
        atomicAdd(&stats[4 + 2 * bb], r1[0] + r1[1] + r1[2] + r1[3]);
        atomicAdd(&stats[5 + 2 * bb], r2[0] + r2[1] + r2[2] + r2[3]);
    }
}

// proj w [co][ci] -> wT [ci][co]
__global__ void transpose_proj_k(const float* __restrict__ w, float* __restrict__ wT) {
    int ci = blockIdx.x, co = threadIdx.x;
    wT[(size_t)ci * 256 + co] = w[(size_t)co * 256 + ci];
}

// ------- 1x1 conv, fused: GN-cn on load, +bias, silu, y = x + ca*mix -> C
__global__ __launch_bounds__(256) void proj_fused_k(
    const float* __restrict__ src, const float* __restrict__ wT,
    const float* __restrict__ bias, const float* __restrict__ stats,
    const float* __restrict__ cnw, const float* __restrict__ cnb,
    const float* __restrict__ xin, const float* __restrict__ cap,
    float* __restrict__ dst)
{
    int bb = blockIdx.x >> 9, pxc = blockIdx.x & 511;
    size_t pix0 = (size_t)pxc * 32;
    int tid = threadIdx.x;
    int co = tid;
    float mean = stats[4 + 2 * bb] * (1.f / CHW);
    float var  = stats[5 + 2 * bb] * (1.f / CHW) - mean * mean;
    float rsv  = rsqrtf(var + 1e-5f);
    float ca = cap[0];
    __shared__ __align__(16) float in_s[64][32];
    __shared__ float outs[256 * 33];
    float acc[32];
    #pragma unroll
    for (int p = 0; p < 32; p++) acc[p] = 0.f;

    for (int ci0 = 0; ci0 < 256; ci0 += 64) {
        __syncthreads();
        {
            int lci = tid >> 2, lp = (tid & 3) * 8;
            int ch = ci0 + lci;
            float sc = rsv * cnw[ch];
            float sh = cnb[ch] - mean * sc;
            const float* sp = src + ((size_t)(bb * 256 + ch)) * HW + pix0 + lp;
            float4 v0 = *(const float4*)(sp);
            float4 v1 = *(const float4*)(sp + 4);
            v0.x = v0.x * sc + sh; v0.y = v0.y * sc + sh;
            v0.z = v0.z * sc + sh; v0.w = v0.w * sc + sh;
            v1.x = v1.x * sc + sh; v1.y = v1.y * sc + sh;
            v1.z = v1.z * sc + sh; v1.w = v1.w * sc + sh;
            *(float4*)&in_s[lci][lp]     = v0;
            *(float4*)&in_s[lci][lp + 4] = v1;
        }
        __syncthreads();
        for (int ci = 0; ci < 64; ci++) {
            float wv = wT[(size_t)(ci0 + ci) * 256 + co];
            #pragma unroll
            for (int p4 = 0; p4 < 8; p4++) {
                float4 iv = *(const float4*)&in_s[ci][p4 * 4];
                acc[p4 * 4 + 0] = fmaf(wv, iv.x, acc[p4 * 4 + 0]);
                acc[p4 * 4 + 1] = fmaf(wv, iv.y, acc[p4 * 4 + 1]);
                acc[p4 * 4 + 2] = fmaf(wv, iv.z, acc[p4 * 4 + 2]);
                acc[p4 * 4 + 3] = fmaf(wv, iv.w, acc[p4 * 4 + 3]);
            }
        }
    }
    float bv = bias[co];
    #pragma unroll
    for (int p = 0; p < 32; p++) outs[co * 33 + p] = acc[p] + bv;
    __syncthreads();
    for (int idx = tid; idx < 8192; idx += 256) {
        int px = idx & 31, c = idx >> 5;
        float v = outs[c * 33 + px];
        v = v / (1.f + expf(-v));
        size_t ga = ((size_t)(bb * 256 + c)) * HW + pix0 + px;
        dst[ga] = xin[ga] + ca * v;
    }
}

// ------------------------------------------------ prep: weights -> split bf16
// rc_w fp32 [co][ci][5][5] -> Ws[cib][ky][kx][co][64k] bf16, LINEAR units
// (k-units 0..3 = hi of ci 0..31, 4..7 = lo). Read directly by conv (global).
__global__ __launch_bounds__(256) void prep_w_k(
    const float* __restrict__ w, u16* __restrict__ Ws)
{
    int idx = blockIdx.x * 256 + threadIdx.x;
    int u = idx & 7; int t = idx >> 3;
    int co = t & 255; t >>= 8;
    int kx = t % 5; t /= 5;
    int ky = t % 5; t /= 5;
    int cib = t;
    int lo = (u >= 4);
    int ci0 = cib * 32 + (u & 3) * 8;
    u16 vals[8];
    #pragma unroll
    for (int j = 0; j < 8; ++j) {
        float wv = w[(((size_t)co * 256 + (ci0 + j)) * 5 + ky) * 5 + kx];
        u16 h = f2bf(wv);
        vals[j] = lo ? f2bf(wv - bf2f(h)) : h;
    }
    uint4 v;
    v.x = (unsigned)vals[0] | ((unsigned)vals[1] << 16);
    v.y = (unsigned)vals[2] | ((unsigned)vals[3] << 16);
    v.z = (unsigned)vals[4] | ((unsigned)vals[5] << 16);
    v.w = (unsigned)vals[6] | ((unsigned)vals[7] << 16);
    *(uint4*)(Ws + (size_t)idx * 8) = v;
}

// -------------------- prep: GN16 + silu + split + transpose -> XtG (padded)
// src fp32 NCHW -> XtG[b][cib][ys=y+2][xs=x+2][64] bf16, row = hi(32)|lo(32),
// 16B units stored at u' = u ^ (xs&7). grid = 2b*128y*4xc = 1024.
__global__ __launch_bounds__(256) void prep_xtg_k(
    const float* __restrict__ src, const float* __restrict__ stats,
    const float* __restrict__ gw, const float* __restrict__ gb,
    u16* __restrict__ XtG)
{
    int bb = blockIdx.x >> 9, rem = blockIdx.x & 511;
    int yy = rem >> 2, xc = rem & 3;
    __shared__ float tile[256][33];
    int tid = threadIdx.x;
    int xx = tid & 31, cg = tid >> 5;          // cg == cib
    int x0 = xc * 32;
    for (int i = tid; i < 8192; i += 256) {
        int c = i >> 5, xl = i & 31;
        tile[c][xl] = src[((size_t)(bb * 256 + c) * 128 + yy) * 128 + x0 + xl];
    }
    __syncthreads();
    int x = x0 + xx;
    u16 vals[64];
    #pragma unroll
    for (int ci = 0; ci < 32; ++ci) {
        int c = cg * 32 + ci;
        int g = bb * 16 + (c >> 4);
        float mean = stats[2 * g] * (1.f / 262144.f);
        float var  = stats[2 * g + 1] * (1.f / 262144.f) - mean * mean;
        float rsv  = rsqrtf(var + 1e-5f);
        float v = (tile[c][xx] - mean) * rsv * gw[c] + gb[c];
        v = v / (1.f + expf(-v));
        u16 h = f2bf(v);
        float lo = v - bf2f(h);
        vals[(ci >> 3) * 8 + (ci & 7)]      = h;
        vals[32 + (ci >> 3) * 8 + (ci & 7)] = f2bf(lo);
    }
    int sxz = (x + 2) & 7;
    u16* base = XtG + ((((size_t)bb * 8 + cg) * 134 + (yy + 2)) * 134 + (x + 2)) * 64;
    #pragma unroll
    for (int u = 0; u < 8; ++u) {
        uint4 v;
        v.x = (unsigned)vals[u*8+0] | ((unsigned)vals[u*8+1] << 16);
        v.y = (unsigned)vals[u*8+2] | ((unsigned)vals[u*8+3] << 16);
        v.z = (unsigned)vals[u*8+4] | ((unsigned)vals[u*8+5] << 16);
        v.w = (unsigned)vals[u*8+6] | ((unsigned)vals[u*8+7] << 16);
        *(uint4*)(base + (u ^ sxz) * 8) = v;
    }
}

// --------------------------------------- conv5x5 via split-bf16 MFMA GEMM
// 2-phase pipelined: A ring of 8 row slots in LDS (prefetch 1 step ahead via
// global_load_lds), W fragments read directly from global (L2). One raw
// s_barrier + vmcnt(0) per (cib,ky) step. XCD-swizzled bid.
__global__ __launch_bounds__(256, 1) void conv_mfma_k(
    const u16* __restrict__ XtG, const u16* __restrict__ Ws,
    const float* __restrict__ bias, const float* __restrict__ addbuf,
    float* __restrict__ dst, float* __restrict__ tstats)
{
    __shared__ u16 Abuf[8][136][64];   // 139264 B
    __shared__ float g1s[4], g2s[4];

    int bid = blockIdx.x;
    int xcd = bid & 7, j = bid >> 3;   // round-robin XCD heuristic
    int coq = xcd >> 1;                // each XCD: fixed (coq, b) -> W set 1.6MB
    int b   = xcd & 1;
    int y0  = j * 4;
    int co0 = coq * 64;
    int tid  = threadIdx.x;
    int lane = tid & 63, wv = tid >> 6;
    int l15 = lane & 15, lg = lane >> 4;
    int y = y0 + wv;

    const size_t plane = (size_t)134 * 134 * 64;
    const u16* Xb = XtG + (size_t)b * 8 * plane;

    f32x4 acc[8][4];
    #pragma unroll
    for (int m = 0; m < 8; ++m)
        #pragma unroll
        for (int nf = 0; nf < 4; ++nf)
            acc[m][nf] = (f32x4){0.f, 0.f, 0.f, 0.f};

    // prologue: rows for (cib=0, ky=0): source rows ys = y0..y0+3
    #pragma unroll
    for (int rr = 0; rr < 4; ++rr)
        stage_lin((const char*)(Xb + (size_t)(y0 + rr) * (134 * 64)),
                  (char*)&Abuf[(y0 + rr - 2) & 7][0][0], 132 * 128);
    asm volatile("s_waitcnt vmcnt(0)" ::: "memory");
    __builtin_amdgcn_sched_barrier(0);
    __builtin_amdgcn_s_barrier();
    __builtin_amdgcn_sched_barrier(0);

    for (int cib = 0; cib < 8; ++cib) {
        const u16* Xc = Xb + (size_t)cib * plane;
        for (int ky = 0; ky < 5; ++ky) {
            // prefetch next step's A rows (into slots disjoint from this
            // step's read set: read rows y0+ky-2..y0+ky+1 mod 8)
            if (ky < 4) {
                int ys = y0 + ky + 4;                       // input row y0+ky+2
                stage_lin((const char*)(Xc + (size_t)ys * (134 * 64)),
                          (char*)&Abuf[(ys - 2) & 7][0][0], 132 * 128);
            } else if (cib < 7) {
                const u16* Xn = Xb + (size_t)(cib + 1) * plane;
                #pragma unroll
                for (int rr = 0; rr < 4; ++rr)
                    stage_lin((const char*)(Xn + (size_t)(y0 + rr) * (134 * 64)),
                              (char*)&Abuf[(y0 + rr - 2) & 7][0][0], 132 * 128);
            }

            const u16* Ab = &Abuf[(y + ky - 2) & 7][0][0];
            const u16* Wt = Ws + ((size_t)(cib * 5 + ky) * 5) * (256 * 64);
            #pragma unroll
            for (int kx = 0; kx < 5; ++kx) {
                const u16* Wk = Wt + ((size_t)kx * 256 + co0) * 64;
                bf16x8 bh[4], bl[4], ah[8];
                #pragma unroll
                for (int nf = 0; nf < 4; ++nf) {
                    const u16* wp = Wk + (size_t)(nf * 16 + l15) * 64 + lg * 8;
                    bh[nf] = *(const bf16x8*)(wp);
                    bl[nf] = *(const bf16x8*)(wp + 32);
                }
                #pragma unroll
                for (int m = 0; m < 8; ++m) {
                    int xs = m * 16 + l15 + kx;
                    ah[m] = *(const bf16x8*)(Ab + xs * 64 + (lg ^ (xs & 7)) * 8);
                }
                #pragma unroll
                for (int m = 0; m < 8; ++m)
                    #pragma unroll
                    for (int nf = 0; nf < 4; ++nf)
                        acc[m][nf] = MFMA16(ah[m], bh[nf], acc[m][nf]);
                #pragma unroll
                for (int m = 0; m < 8; ++m)
                    #pragma unroll
                    for (int nf = 0; nf < 4; ++nf)
                        acc[m][nf] = MFMA16(ah[m], bl[nf], acc[m][nf]);
                #pragma unroll
                for (int m = 0; m < 8; ++m) {
                    int xs = m * 16 + l15 + kx;
                    ah[m] = *(const bf16x8*)(Ab + xs * 64 + ((lg ^ (xs & 7)) ^ 4) * 8);
                }
                #pragma unroll
                for (int m = 0; m < 8; ++m)
                    #pragma unroll
                    for (int nf = 0; nf < 4; ++nf)
                        acc[m][nf] = MFMA16(ah[m], bh[nf], acc[m][nf]);
            }
            // drain prefetch (it had the whole compute to land), then barrier
            asm volatile("s_waitcnt vmcnt(0)" ::: "memory");
            __builtin_amdgcn_sched_barrier(0);
            __builtin_amdgcn_s_barrier();
            __builtin_amdgcn_sched_barrier(0);
        }
    }

    // epilogue: D row (px) = m*16 + lg*4 + reg ; D col (co) = co0 + nf*16 + l15
    float ts1[4], ts2[4];
    #pragma unroll
    for (int nf = 0; nf < 4; ++nf) { ts1[nf] = 0.f; ts2[nf] = 0.f; }
    #pragma unroll
    for (int nf = 0; nf < 4; ++nf) {
        int co = co0 + nf * 16 + l15;
        float bv = bias[co];
        size_t rowb = ((size_t)(b * 256 + co) * 128 + y) * 128;
        #pragma unroll
        for (int m = 0; m < 8; ++m) {
            size_t ob = rowb + m * 16 + lg * 4;
            f32x4 v = acc[m][nf];
            v.x += bv; v.y += bv; v.z += bv; v.w += bv;
            if (addbuf) {
                float4 r = *(const float4*)(addbuf + ob);
                v.x += r.x; v.y += r.y; v.z += r.z; v.w += r.w;
            }
            *(f32x4*)(dst + ob) = v;
            if (tstats) {
                ts1[nf] += (v.x + v.y) + (v.z + v.w);
                ts2[nf] += (v.x * v.x + v.y * v.y) + (v.z * v.z + v.w * v.w);
            }
        }
    }
    if (tstats) {
        if (tid < 4) { g1s[tid] = 0.f; g2s[tid] = 0.f; }
        __syncthreads();
        #pragma unroll
        for (int nf = 0; nf < 4; ++nf) {
            float a = ts1[nf], c2 = ts2[nf];
            for (int off = 32; off; off >>= 1) {
                a  += __shfl_xor(a, off);
                c2 += __shfl_xor(c2, off);
            }
            if (lane == 0) {
                atomicAdd(&g1s[nf], a);
                atomicAdd(&g2s[nf], c2);
            }
        }
        __syncthreads();
        if (tid < 4) {
            int g = b * 16 + coq * 4 + tid;
            atomicAdd(&tstats[2 * g],     g1s[tid]);
            atomicAdd(&tstats[2 * g + 1], g2s[tid]);
        }
    }
}

// ---------------------------------------------------------------------------
extern "C" void kernel_launch(void* const* d_in, const int* in_sizes, int n_in,
                              void* d_out, int out_size, void* d_ws, size_t ws_size,
                              hipStream_t stream)
{
    (void)in_sizes; (void)n_in; (void)out_size; (void)ws_size;
    const float* x        = (const float*)d_in[0];
    const float* norm1_w  = (const float*)d_in[1];
    const float* norm1_b  = (const float*)d_in[2];
    // d_in[3] (v_w), d_in[4] (v_b): dead code in the reference — skipped.
    const float* proj_w   = (const float*)d_in[5];
    const float* proj_b   = (const float*)d_in[6];
    const float* cn_w     = (const float*)d_in[7];
    const float* cn_b     = (const float*)d_in[8];
    const float* sim_a    = (const float*)d_in[9];
    const float* sim_b    = (const float*)d_in[10];
    const float* con_a    = (const float*)d_in[11];
    const float* rn1_w    = (const float*)d_in[12];
    const float* rn1_b    = (const float*)d_in[13];
    const float* rc1_w    = (const float*)d_in[14];
    const float* rc1_b    = (const float*)d_in[15];
    const float* rn2_w    = (const float*)d_in[16];
    const float* rn2_b    = (const float*)d_in[17];
    const float* rc2_w    = (const float*)d_in[18];
    const float* rc2_b    = (const float*)d_in[19];

    float* ws = (float*)d_ws;
    float* Bb    = ws;                      // [2,256,128,128] fp32
    size_t o = NT;
    float* cf    = ws + o; o += 8192;
    float* dense = ws + o; o += 8192;
    float* simb  = ws + o; o += 1048576;
    float* wTp   = ws + o; o += 65536;
    // zeroed region: stats(256) | den(256) | num(8192) = 8704 floats
    float* stats = ws + o; o += 256;   // x-gn1@0[4], Bb-gn1@4[4], y-gn16@8[64], t-gn16@72[64]
    float* denp  = ws + o; o += 256;
    float* nump  = ws + o; o += 8192;
    u16* XtG = (u16*)(ws + o);              // 2*8*134*134*64 = 18,384,896 u16
    const size_t XTG_ELEMS = 2ull * 8 * 134 * 134 * 64;
    u16* Ws1 = XtG + XTG_ELEMS + 2048;      // 25*8*256*64 = 3,276,800 u16
    u16* Ws2 = Ws1 + 3276800 + 2048;
    float* C = (float*)d_out;               // y buffer aliases the output

    zero_small_k<<<34, 256, 0, stream>>>(stats);           // 34*256 == 8704
    zero_buf_k<<<2048, 256, 0, stream>>>((uint4*)XtG, (int)(XTG_ELEMS / 8));
    prep_w_k<<<1600, 256, 0, stream>>>(rc1_w, Ws1);
    prep_w_k<<<1600, 256, 0, stream>>>(rc2_w, Ws2);
    transpose_proj_k<<<256, 256, 0, stream>>>(proj_w, wTp);

    // GN1(x) stats only; affine folded into cluster kernels
    reduce_stats_k<<<2048, 256, 0, stream>>>(x, stats + 0, CHW, 1024);
    centers_k<<<256, 256, 0, stream>>>(x, stats, norm1_w, norm1_b, cf);
    sim_part_k<<<256, 256, 0, stream>>>(x, stats, norm1_w, norm1_b, cf, simb,
                                        nump, denp, sim_a, sim_b);
    finalize_dense_k<<<32, 256, 0, stream>>>(nump, denp, cf, dense);
    dispatch_k<<<1024, 256, 0, stream>>>(simb, dense, Bb, stats);
    // GN-cn + 1x1 conv + silu + residual, all fused -> C (= y)
    proj_fused_k<<<1024, 256, 0, stream>>>(Bb, wTp, proj_b, stats, cn_w, cn_b,
                                           x, con_a, C);
    // ResnetBlock conv1 (t-stats fused into epilogue)
    reduce_stats_k<<<256, 256, 0, stream>>>(C, stats + 8, 262144, 8);
    prep_xtg_k<<<1024, 256, 0, stream>>>(C, stats + 8, rn1_w, rn1_b, XtG);
    conv_mfma_k<<<256, 256, 0, stream>>>(XtG, Ws1, rc1_b, nullptr, Bb, stats + 72);
    // ResnetBlock conv2 + residual
    prep_xtg_k<<<1024, 256, 0, stream>>>(Bb, stats + 72, rn2_w, rn2_b, XtG);
    conv_mfma_k<<<256, 256, 0, stream>>>(XtG, Ws2, rc2_b, C, C, nullptr);
}

// Round 6
// 1025.452 us; speedup vs baseline: 5.0291x; 1.0220x over previous
//
#include <hip/hip_runtime.h>
#include <math.h>

// ---------------------------------------------------------------------------
// PD_Block, round 5 (resubmit — R5 bench never ran: GPU acquisition timeout).
//  * conv5x5: 8-wave blocks (2 waves/SIMD -> ds_read/MFMA cross-wave overlap),
//    A ring 8 slots + W kx-level LDS double-buffer, per-kx vmcnt(0)+s_barrier
//    (stage issued before MFMA cluster -> drain hidden under compute).
//  * proj 1x1: GN-cn folded into per-batch W' (affine fold), dispatch writes
//    bf16-split swizzled Pt directly, proj = MFMA GEMM with silu + residual +
//    y-GN16 stats fused in epilogue. zero only XtG halo.
// ---------------------------------------------------------------------------

#define NT   8388608ull        // 2*256*128*128
#define CHW  4194304           // 256*128*128
#define HW   16384             // 128*128

typedef unsigned short u16;
typedef __attribute__((ext_vector_type(8))) short bf16x8;
typedef __attribute__((ext_vector_type(4))) float f32x4;

#define MFMA16(a,b,c) __builtin_amdgcn_mfma_f32_16x16x32_bf16(a,b,c,0,0,0)

__device__ __forceinline__ u16 f2bf(float f) {
    unsigned u = __float_as_uint(f);
    unsigned r = (u + 0x7fffu + ((u >> 16) & 1u)) >> 16;
    return (u16)r;
}
__device__ __forceinline__ float bf2f(u16 h) {
    return __uint_as_float((unsigned)h << 16);
}

__device__ __forceinline__ void gll16(const void* g, void* l) {
    __builtin_amdgcn_global_load_lds(
        (const __attribute__((address_space(1))) void*)g,
        (__attribute__((address_space(3))) void*)l, 16, 0, 0);
}
// linear global->LDS copy for 8-wave blocks; may overrun up to +1023 B into
// LDS slot slack; global overruns stay inside the allocated buffer.
__device__ __forceinline__ void stage8(const char* g, char* l, int bytes) {
    int lane = threadIdx.x & 63, wv = threadIdx.x >> 6;
    for (int off = wv << 10; off < bytes; off += 8192)
        gll16(g + off + lane * 16, l + off);
}

#define KXBAR()  do { \
    asm volatile("s_waitcnt vmcnt(0)" ::: "memory"); \
    __builtin_amdgcn_sched_barrier(0); \
    __builtin_amdgcn_s_barrier(); \
    __builtin_amdgcn_sched_barrier(0); } while (0)

// ---------------------------------------------------------------- zero utils
__global__ void zero_small_k(float* __restrict__ p) {
    p[blockIdx.x * 256 + threadIdx.x] = 0.f;     // grid*256 == region size
}
// zero XtG halo rows/cols only (rows ys<2 or >=130 full; else xs {0,1,130,131})
__global__ __launch_bounds__(256) void zero_halo_k(u16* __restrict__ XtG) {
    int plane = blockIdx.x / 134, ys = blockIdx.x % 134;
    u16* row = XtG + ((size_t)plane * 134 + ys) * 134 * 64;
    uint4 z = make_uint4(0u, 0u, 0u, 0u);
    if (ys < 2 || ys >= 130) {
        for (int i = threadIdx.x; i < 1072; i += 256) ((uint4*)row)[i] = z;
    } else if (threadIdx.x < 32) {
        int xi = threadIdx.x >> 3;
        int xs = (xi < 2) ? xi : 128 + xi;       // 0,1,130,131
        ((uint4*)(row + xs * 64))[threadIdx.x & 7] = z;
    }
}

// ------------------------------------------------- generic group-stat reduce
__global__ __launch_bounds__(256) void reduce_stats_k(
    const float* __restrict__ src, float* __restrict__ stats,
    int elems_per_group, int blocks_per_group)
{
    int g   = blockIdx.x / blocks_per_group;
    int blk = blockIdx.x % blocks_per_group;
    int per_block = elems_per_group / blocks_per_group;
    const float* p = src + (size_t)g * elems_per_group + (size_t)blk * per_block;
    float s = 0.f, ss = 0.f;
    for (int i = threadIdx.x * 4; i < per_block; i += 256 * 4) {
        float4 v = *(const float4*)(p + i);
        s  += (v.x + v.y) + (v.z + v.w);
        ss += (v.x * v.x + v.y * v.y) + (v.z * v.z + v.w * v.w);
    }
    for (int off = 32; off; off >>= 1) {
        s  += __shfl_down(s, off);
        ss += __shfl_down(ss, off);
    }
    __shared__ float rs[4], rss[4];
    int lane = threadIdx.x & 63, wv = threadIdx.x >> 6;
    if (lane == 0) { rs[wv] = s; rss[wv] = ss; }
    __syncthreads();
    if (threadIdx.x == 0) {
        atomicAdd(&stats[2 * g],     rs[0] + rs[1] + rs[2] + rs[3]);
        atomicAdd(&stats[2 * g + 1], rss[0] + rss[1] + rss[2] + rss[3]);
    }
}

// --------------------------- cluster: centers (pool raw x, then GN1 affine)
__global__ __launch_bounds__(256) void centers_k(
    const float* __restrict__ x, const float* __restrict__ stats,
    const float* __restrict__ n1w, const float* __restrict__ n1b,
    float* __restrict__ cf)
{
    int sm = blockIdx.x;
    int m = sm & 3, s = sm >> 2;
    int f3 = s & 1, f2 = (s >> 1) & 1, head = (s >> 2) & 7, bb = s >> 5;
    int mh = m & 1, mw = m >> 1;
    int c = threadIdx.x & 31, grp = threadIdx.x >> 5;
    const float* base = x + ((size_t)(bb * 256 + head * 32 + c) * 128
                             + f2 * 64 + mw * 32) * 128 + f3 * 64 + mh * 32;
    float sum = 0.f;
    for (int r = grp; r < 32; r += 8) {
        const float* row = base + r * 128;
        #pragma unroll
        for (int q = 0; q < 8; q++) {
            float4 v = *(const float4*)(row + q * 4);
            sum += (v.x + v.y) + (v.z + v.w);
        }
    }
    __shared__ float red[8][32];
    red[grp][c] = sum;
    __syncthreads();
    if (grp == 0) {
        float t = 0.f;
        #pragma unroll
        for (int k = 0; k < 8; k++) t += red[k][c];
        float mean = stats[2 * bb] * (1.f / CHW);
        float var  = stats[2 * bb + 1] * (1.f / CHW) - mean * mean;
        float rsv  = rsqrtf(var + 1e-5f);
        int ch = head * 32 + c;
        float sc = rsv * n1w[ch];
        float sh = n1b[ch] - mean * sc;
        cf[(size_t)sm * 32 + c] = (t * (1.f / 1024.f)) * sc + sh;
    }
}

// --------------- cluster: sim + partial num/den (4 blocks per s, atomics)
__global__ __launch_bounds__(256) void sim_part_k(
    const float* __restrict__ x, const float* __restrict__ stats,
    const float* __restrict__ n1w, const float* __restrict__ n1b,
    const float* __restrict__ cf, float* __restrict__ simb,
    float* __restrict__ nump, float* __restrict__ denp,
    const float* __restrict__ alphap, const float* __restrict__ betap)
{
    int sq = blockIdx.x;
    int q = sq & 3, s = sq >> 2;
    int f3 = s & 1, f2 = (s >> 1) & 1, head = (s >> 2) & 7, bb = s >> 5;
    int tid = threadIdx.x;
    float alpha = alphap[0], beta = betap[0];

    __shared__ float cfr[4][32], cfn[4][32], invn[4], scs[32], shs[32];
    if (tid < 128) {
        int m = tid >> 5, c = tid & 31;
        cfr[m][c] = cf[(size_t)(s * 4 + m) * 32 + c];
    }
    if (tid >= 128 && tid < 160) {
        int c = tid - 128;
        float mean = stats[2 * bb] * (1.f / CHW);
        float var  = stats[2 * bb + 1] * (1.f / CHW) - mean * mean;
        float rsv  = rsqrtf(var + 1e-5f);
        int ch = head * 32 + c;
        float sc = rsv * n1w[ch];
        scs[c] = sc;
        shs[c] = n1b[ch] - mean * sc;
    }
    __syncthreads();
    if (tid < 4) {
        float n = 0.f;
        for (int c = 0; c < 32; c++) n += cfr[tid][c] * cfr[tid][c];
        invn[tid] = 1.f / fmaxf(sqrtf(n), 1e-12f);
    }
    __syncthreads();
    if (tid < 128) {
        int m = tid >> 5, c = tid & 31;
        cfn[m][c] = cfr[m][c] * invn[m];
    }
    __syncthreads();

    const float* xbase = x + ((size_t)(bb * 256 + head * 32) * 128 + f2 * 64) * 128
                           + f3 * 64;
    float num[4][32];
    float den[4] = {0.f, 0.f, 0.f, 0.f};
    #pragma unroll
    for (int m = 0; m < 4; m++)
        #pragma unroll
        for (int c = 0; c < 32; c++) num[m][c] = 0.f;

    for (int n0 = 0; n0 < 1024; n0 += 256) {
        int n = q * 1024 + n0 + tid;
        int w = n >> 6, h = n & 63;
        const float* px = xbase + w * 128 + h;
        float f[32]; float ss = 0.f;
        #pragma unroll
        for (int c = 0; c < 32; c++) {
            f[c] = px[(size_t)c * HW] * scs[c] + shs[c];
            ss += f[c] * f[c];
        }
        float inv = 1.f / fmaxf(sqrtf(ss), 1e-12f);
        #pragma unroll
        for (int m = 0; m < 4; m++) {
            float dot = 0.f;
            #pragma unroll
            for (int c = 0; c < 32; c++) dot += cfn[m][c] * f[c];
            float z = beta + alpha * dot * inv;
            float sv = 1.f / (1.f + expf(-z));
            simb[((size_t)s * 4 + m) * 4096 + n] = sv;
            den[m] += sv;
            #pragma unroll
            for (int c = 0; c < 32; c++) num[m][c] = fmaf(sv, f[c], num[m][c]);
        }
    }

    __shared__ float rnum[4][128];
    __shared__ float rden[4][4];
    int lane = tid & 63, wv = tid >> 6;
    #pragma unroll
    for (int m = 0; m < 4; m++) {
        #pragma unroll
        for (int c = 0; c < 32; c++) {
            float v = num[m][c];
            for (int off = 32; off; off >>= 1) v += __shfl_xor(v, off);
            if (lane == 0) rnum[wv][m * 32 + c] = v;
        }
        float d = den[m];
        for (int off = 32; off; off >>= 1) d += __shfl_xor(d, off);
        if (lane == 0) rden[wv][m] = d;
    }
    __syncthreads();
    if (tid < 4)
        atomicAdd(&denp[s * 4 + tid],
                  rden[0][tid] + rden[1][tid] + rden[2][tid] + rden[3][tid]);
    if (tid < 128) {
        int m = tid >> 5, c = tid & 31;
        float nsum = rnum[0][tid] + rnum[1][tid] + rnum[2][tid] + rnum[3][tid];
        atomicAdd(&nump[(size_t)(s * 4 + m) * 32 + c], nsum);
    }
}

// ------------------------------------------------------- finalize dense_out
__global__ void finalize_dense_k(const float* __restrict__ nump,
                                 const float* __restrict__ denp,
                                 const float* __restrict__ cf,
                                 float* __restrict__ dense)
{
    int i = blockIdx.x * 256 + threadIdx.x;   // 32 blocks * 256 = 8192
    dense[i] = (nump[i] + cf[i]) / (denp[i >> 5] + 1.0f);
}

// ------- cluster dispatch: write Pt bf16-split swizzled + fused Bb GN1 stats
// Pt[b][cib=head][px(16384)][64k], 16B units at u' = u^(px&7)
__global__ __launch_bounds__(256) void dispatch_k(
    const float* __restrict__ simb, const float* __restrict__ dense,
    u16* __restrict__ Pt, float* __restrict__ stats)
{
    int s = blockIdx.x >> 4, chunk = blockIdx.x & 15;
    int tid = threadIdx.x;
    __shared__ float dl[4][32];
    if (tid < 128) {
        int m = tid >> 5, c = tid & 31;
        dl[m][c] = dense[(size_t)(s * 4 + m) * 32 + c];
    }
    __syncthreads();
    int n = chunk * 256 + tid;
    int w = n >> 6, h = n & 63;
    int f3 = s & 1, f2 = (s >> 1) & 1, head = (s >> 2) & 7, bb = s >> 5;
    float sv[4];
    #pragma unroll
    for (int m = 0; m < 4; m++) sv[m] = simb[((size_t)s * 4 + m) * 4096 + n];
    int px = (f2 * 64 + w) * 128 + (f3 * 64 + h);
    u16 vals[64];
    float s1 = 0.f, s2 = 0.f;
    #pragma unroll
    for (int c = 0; c < 32; c++) {
        float v = dl[0][c] * sv[0] + dl[1][c] * sv[1]
                + dl[2][c] * sv[2] + dl[3][c] * sv[3];
        s1 += v; s2 += v * v;
        u16 hi = f2bf(v);
        vals[(c >> 3) * 8 + (c & 7)]      = hi;
        vals[32 + (c >> 3) * 8 + (c & 7)] = f2bf(v - bf2f(hi));
    }
    u16* base = Pt + (((size_t)bb * 8 + head) * 16384 + px) * 64;
    int sw = px & 7;
    #pragma unroll
    for (int u = 0; u < 8; ++u) {
        uint4 v;
        v.x = (unsigned)vals[u*8+0] | ((unsigned)vals[u*8+1] << 16);
        v.y = (unsigned)vals[u*8+2] | ((unsigned)vals[u*8+3] << 16);
        v.z = (unsigned)vals[u*8+4] | ((unsigned)vals[u*8+5] << 16);
        v.w = (unsigned)vals[u*8+6] | ((unsigned)vals[u*8+7] << 16);
        *(uint4*)(base + (u ^ sw) * 8) = v;
    }
    for (int off = 32; off; off >>= 1) {
        s1 += __shfl_xor(s1, off);
        s2 += __shfl_xor(s2, off);
    }
    __shared__ float r1[4], r2[4];
    int lane = tid & 63, wv = tid >> 6;
    if (lane == 0) { r1[wv] = s1; r2[wv] = s2; }
    __syncthreads();
    if (tid == 0) {
        atomicAdd(&stats[4 + 2 * bb], r1[0] + r1[1] + r1[2] + r1[3]);
        atomicAdd(&stats[5 + 2 * bb], r2[0] + r2[1] + r2[2] + r2[3]);
    }
}

// ------------- prep proj weights: W'[b][cib][co][64k] = w*sc (GN-cn folded),
// bias'[b][co] = pb[co] + sum_ci w*sh. grid 512 = (b,co), 256 thr = ci.
__global__ __launch_bounds__(256) void prep_wp_k(
    const float* __restrict__ w, const float* __restrict__ pb,
    const float* __restrict__ stats, const float* __restrict__ cnw,
    const float* __restrict__ cnb, u16* __restrict__ Wp,
    float* __restrict__ biasp)
{
    int b = blockIdx.x >> 8, co = blockIdx.x & 255;
    int ci = threadIdx.x;
    float mean = stats[4 + 2 * b] * (1.f / CHW);
    float var  = stats[5 + 2 * b] * (1.f / CHW) - mean * mean;
    float rsv  = rsqrtf(var + 1e-5f);
    float sc = rsv * cnw[ci];
    float sh = cnb[ci] - mean * sc;
    float wv = w[(size_t)co * 256 + ci];
    float wp = wv * sc;
    u16 hi = f2bf(wp);
    u16 lo = f2bf(wp - bf2f(hi));
    __shared__ u16 buf[512];
    __shared__ float red[256];
    int cib = ci >> 5, cl = ci & 31;
    buf[cib * 64 + (cl >> 3) * 8 + (cl & 7)]      = hi;
    buf[cib * 64 + 32 + (cl >> 3) * 8 + (cl & 7)] = lo;
    red[ci] = wv * sh;
    __syncthreads();
    if (ci < 64) {
        int cb = ci >> 3, up = ci & 7;
        int u = up ^ (co & 7);
        const u16* o = &buf[cb * 64 + u * 8];
        uint4 v;
        v.x = (unsigned)o[0] | ((unsigned)o[1] << 16);
        v.y = (unsigned)o[2] | ((unsigned)o[3] << 16);
        v.z = (unsigned)o[4] | ((unsigned)o[5] << 16);
        v.w = (unsigned)o[6] | ((unsigned)o[7] << 16);
        *(uint4*)(Wp + (((size_t)b * 8 + cb) * 256 + co) * 64 + up * 8) = v;
    }
    for (int st = 128; st; st >>= 1) {
        if (ci < st) red[ci] += red[ci + st];
        __syncthreads();
    }
    if (ci == 0) biasp[b * 256 + co] = pb[co] + red[0];
}

// ----------- proj MFMA GEMM: y = x + ca*silu(Pt x W' + bias'), + y GN16 stats
// grid 256 = (b, px-tile 128px); 8 waves = (pxH 2, coQ 4); wave 64px x 64co.
__global__ __launch_bounds__(512, 2) void proj_gemm_k(
    const u16* __restrict__ Pt, const u16* __restrict__ Wp,
    const float* __restrict__ biasp, const float* __restrict__ xin,
    const float* __restrict__ cap, float* __restrict__ dst,
    float* __restrict__ ystats)
{
    __shared__ u16 Apt[2][128][64];    // 32 KB
    __shared__ u16 Wl[2][256][64];     // 64 KB
    int bid = blockIdx.x;
    int b = bid >> 7, t = bid & 127;
    int px0 = t * 128;
    int tid = threadIdx.x, lane = tid & 63, wv = tid >> 6;
    int pxH = wv & 1, coQ = wv >> 1;
    int l15 = lane & 15, lg = lane >> 4;
    float ca = cap[0];
    const u16* Ptb = Pt + (size_t)b * 8 * 16384 * 64;
    const u16* Wpb = Wp + (size_t)b * 8 * 256 * 64;

    f32x4 acc[4][4];
    #pragma unroll
    for (int m = 0; m < 4; ++m)
        #pragma unroll
        for (int nf = 0; nf < 4; ++nf)
            acc[m][nf] = (f32x4){0.f, 0.f, 0.f, 0.f};

    stage8((const char*)(Ptb + (size_t)px0 * 64), (char*)&Apt[0][0][0], 16384);
    stage8((const char*)(Wpb), (char*)&Wl[0][0][0], 32768);
    KXBAR();

    for (int cib = 0; cib < 8; ++cib) {
        int cur = cib & 1;
        if (cib < 7) {
            stage8((const char*)(Ptb + ((size_t)(cib + 1) * 16384 + px0) * 64),
                   (char*)&Apt[cur ^ 1][0][0], 16384);
            stage8((const char*)(Wpb + (size_t)(cib + 1) * 256 * 64),
                   (char*)&Wl[cur ^ 1][0][0], 32768);
        }
        bf16x8 ah[4], al[4], wh[4], wl_[4];
        #pragma unroll
        for (int m = 0; m < 4; ++m) {
            int pxl = pxH * 64 + m * 16 + l15;
            const u16* pa = &Apt[cur][pxl][0];
            int sz = lg ^ (pxl & 7);
            ah[m] = *(const bf16x8*)(pa + sz * 8);
            al[m] = *(const bf16x8*)(pa + (sz ^ 4) * 8);
        }
        #pragma unroll
        for (int nf = 0; nf < 4; ++nf) {
            int cr = coQ * 64 + nf * 16 + l15;
            const u16* pw = &Wl[cur][cr][0];
            int sz = lg ^ (cr & 7);
            wh[nf]  = *(const bf16x8*)(pw + sz * 8);
            wl_[nf] = *(const bf16x8*)(pw + (sz ^ 4) * 8);
        }
        #pragma unroll
        for (int m = 0; m < 4; ++m)
            #pragma unroll
            for (int nf = 0; nf < 4; ++nf)
                acc[m][nf] = MFMA16(ah[m], wh[nf], acc[m][nf]);
        #pragma unroll
        for (int m = 0; m < 4; ++m)
            #pragma unroll
            for (int nf = 0; nf < 4; ++nf)
                acc[m][nf] = MFMA16(al[m], wh[nf], acc[m][nf]);
        #pragma unroll
        for (int m = 0; m < 4; ++m)
            #pragma unroll
            for (int nf = 0; nf < 4; ++nf)
                acc[m][nf] = MFMA16(ah[m], wl_[nf], acc[m][nf]);
        KXBAR();
    }

    #pragma unroll
    for (int nf = 0; nf < 4; ++nf) {
        int co = coQ * 64 + nf * 16 + l15;
        float bv = biasp[b * 256 + co];
        float s1 = 0.f, s2 = 0.f;
        #pragma unroll
        for (int m = 0; m < 4; ++m) {
            int px = px0 + pxH * 64 + m * 16 + lg * 4;
            size_t ga = ((size_t)(b * 256 + co)) * HW + px;
            f32x4 v = acc[m][nf];
            float o[4] = { v.x + bv, v.y + bv, v.z + bv, v.w + bv };
            float4 xr = *(const float4*)(xin + ga);
            float xa[4] = { xr.x, xr.y, xr.z, xr.w };
            f32x4 yv;
            #pragma unroll
            for (int k = 0; k < 4; ++k) {
                float sl = o[k] / (1.f + expf(-o[k]));
                float yy = xa[k] + ca * sl;
                ((float*)&yv)[k] = yy;
                s1 += yy; s2 += yy * yy;
            }
            *(f32x4*)(dst + ga) = yv;
        }
        for (int off = 32; off; off >>= 1) {
            s1 += __shfl_xor(s1, off);
            s2 += __shfl_xor(s2, off);
        }
        if (lane == 0) {
            int g = b * 16 + coQ * 4 + nf;
            atomicAdd(&ystats[2 * g],     s1);
            atomicAdd(&ystats[2 * g + 1], s2);
        }
    }
}

// ------------------------------------------------ prep: weights -> split bf16
// rc_w fp32 [co][ci][5][5] -> Ws[cib][ky][kx][co][64k] bf16, 16B units at
// swizzled position u' = u ^ (co&7). grid 1600 x 256.
__global__ __launch_bounds__(256) void prep_w_k(
    const float* __restrict__ w, u16* __restrict__ Ws)
{
    int idx = blockIdx.x * 256 + threadIdx.x;
    int up = idx & 7; int t = idx >> 3;
    int co = t & 255; t >>= 8;
    int kx = t % 5; t /= 5;
    int ky = t % 5; t /= 5;
    int cib = t;
    int u = up ^ (co & 7);
    int lo = (u >= 4);
    int ci0 = cib * 32 + (u & 3) * 8;
    u16 vals[8];
    #pragma unroll
    for (int j = 0; j < 8; ++j) {
        float wv = w[(((size_t)co * 256 + (ci0 + j)) * 5 + ky) * 5 + kx];
        u16 h = f2bf(wv);
        vals[j] = lo ? f2bf(wv - bf2f(h)) : h;
    }
    uint4 v;
    v.x = (unsigned)vals[0] | ((unsigned)vals[1] << 16);
    v.y = (unsigned)vals[2] | ((unsigned)vals[3] << 16);
    v.z = (unsigned)vals[4] | ((unsigned)vals[5] << 16);
    v.w = (unsigned)vals[6] | ((unsigned)vals[7] << 16);
    *(uint4*)(Ws + (size_t)idx * 8) = v;
}

// -------------------- prep: GN16 + silu + split + transpose -> XtG (padded)
__global__ __launch_bounds__(256) void prep_xtg_k(
    const float* __restrict__ src, const float* __restrict__ stats,
    const float* __restrict__ gw, const float* __restrict__ gb,
    u16* __restrict__ XtG)
{
    int bb = blockIdx.x >> 9, rem = blockIdx.x & 511;
    int yy = rem >> 2, xc = rem & 3;
    __shared__ float tile[256][33];
    int tid = threadIdx.x;
    int xx = tid & 31, cg = tid >> 5;          // cg == cib
    int x0 = xc * 32;
    for (int i = tid; i < 8192; i += 256) {
        int c = i >> 5, xl = i & 31;
        tile[c][xl] = src[((size_t)(bb * 256 + c) * 128 + yy) * 128 + x0 + xl];
    }
    __syncthreads();
    int x = x0 + xx;
    u16 vals[64];
    #pragma unroll
    for (int ci = 0; ci < 32; ++ci) {
        int c = cg * 32 + ci;
        int g = bb * 16 + (c >> 4);
        float mean = stats[2 * g] * (1.f / 262144.f);
        float var  = stats[2 * g + 1] * (1.f / 262144.f) - mean * mean;
        float rsv  = rsqrtf(var + 1e-5f);
        float v = (tile[c][xx] - mean) * rsv * gw[c] + gb[c];
        v = v / (1.f + expf(-v));
        u16 h = f2bf(v);
        float lo = v - bf2f(h);
        vals[(ci >> 3) * 8 + (ci & 7)]      = h;
        vals[32 + (ci >> 3) * 8 + (ci & 7)] = f2bf(lo);
    }
    int sxz = (x + 2) & 7;
    u16* base = XtG + ((((size_t)bb * 8 + cg) * 134 + (yy + 2)) * 134 + (x + 2)) * 64;
    #pragma unroll
    for (int u = 0; u < 8; ++u) {
        uint4 v;
        v.x = (unsigned)vals[u*8+0] | ((unsigned)vals[u*8+1] << 16);
        v.y = (unsigned)vals[u*8+2] | ((unsigned)vals[u*8+3] << 16);
        v.z = (unsigned)vals[u*8+4] | ((unsigned)vals[u*8+5] << 16);
        v.w = (unsigned)vals[u*8+6] | ((unsigned)vals[u*8+7] << 16);
        *(uint4*)(base + (u ^ sxz) * 8) = v;
    }
}

// --------------------------------------- conv5x5 via split-bf16 MFMA GEMM
// 8 waves (2/SIMD): wave = row r (0..3) x x-half (64px) x 64co.
// A ring 8 slots; W kx-level LDS dbuf; per-kx vmcnt(0)+s_barrier.
__global__ __launch_bounds__(512, 2) void conv_mfma_k(
    const u16* __restrict__ XtG, const u16* __restrict__ Ws,
    const float* __restrict__ bias, const float* __restrict__ addbuf,
    float* __restrict__ dst, float* __restrict__ tstats)
{
    __shared__ u16 Abuf[8][136][64];   // 139,264 B
    __shared__ u16 Wlds[2][64][64];    //  16,384 B

    int bid = blockIdx.x;
    int xcd = bid & 7, j = bid >> 3;
    int coq = xcd >> 1, b = xcd & 1;   // each XCD: one (coq,b) -> W set < L2
    int y0 = j * 4, co0 = coq * 64;
    int tid = threadIdx.x, lane = tid & 63, wv = tid >> 6;
    int r = wv >> 1, xh = wv & 1;
    int l15 = lane & 15, lg = lane >> 4;
    int y = y0 + r, xb = xh * 64;

    const size_t plane = (size_t)134 * 134 * 64;
    const size_t rowsz = (size_t)134 * 64;
    const u16* Xb  = XtG + (size_t)b * 8 * plane;
    const u16* Wco = Ws + (size_t)co0 * 64;

    f32x4 acc[4][4];
    #pragma unroll
    for (int m = 0; m < 4; ++m)
        #pragma unroll
        for (int nf = 0; nf < 4; ++nf)
            acc[m][nf] = (f32x4){0.f, 0.f, 0.f, 0.f};

    // prologue: A rows y0..y0+3 of cib0, W(0,0,0) -> Wlds[0]
    #pragma unroll
    for (int rr = 0; rr < 4; ++rr)
        stage8((const char*)(Xb + (size_t)(y0 + rr) * rowsz),
               (char*)&Abuf[(y0 + rr - 2) & 7][0][0], 16896);
    stage8((const char*)(Wco), (char*)&Wlds[0][0][0], 8192);
    KXBAR();

    int p = 0;
    for (int cib = 0; cib < 8; ++cib) {
        for (int ky = 0; ky < 5; ++ky) {
            const u16* Ab = &Abuf[(y + ky - 2) & 7][0][0];
            #pragma unroll
            for (int i = 0; i < 5; ++i) {
                const u16* Wb = &Wlds[p][0][0];
                bf16x8 wh[4], wl_[4], ah[4], al[4];
                #pragma unroll
                for (int nf = 0; nf < 4; ++nf) {
                    int cr = nf * 16 + l15;
                    int sz = lg ^ (cr & 7);
                    const u16* pw = Wb + cr * 64;
                    wh[nf]  = *(const bf16x8*)(pw + sz * 8);
                    wl_[nf] = *(const bf16x8*)(pw + (sz ^ 4) * 8);
                }
                #pragma unroll
                for (int m = 0; m < 4; ++m) {
                    int xs = xb + m * 16 + l15 + i;
                    int sz = lg ^ (xs & 7);
                    const u16* pa = Ab + xs * 64;
                    ah[m] = *(const bf16x8*)(pa + sz * 8);
                    al[m] = *(const bf16x8*)(pa + (sz ^ 4) * 8);
                }
                // issue next-kx W stage (and A stage at i==1)
                {
                    int ncib = cib, nky = ky, nkx = i + 1;
                    if (nkx == 5) { nkx = 0; nky++; if (nky == 5) { nky = 0; ncib++; } }
                    if (ncib < 8)
                        stage8((const char*)(Wco +
                               (size_t)((ncib * 5 + nky) * 5 + nkx) * (256 * 64)),
                               (char*)&Wlds[p ^ 1][0][0], 8192);
                }
                if (i == 1) {
                    if (ky < 4) {
                        stage8((const char*)(Xb + (size_t)cib * plane
                                             + (size_t)(y0 + ky + 4) * rowsz),
                               (char*)&Abuf[(y0 + ky + 2) & 7][0][0], 16896);
                    } else if (cib < 7) {
                        const char* Xn = (const char*)(Xb + (size_t)(cib + 1) * plane);
                        #pragma unroll
                        for (int rr = 0; rr < 4; ++rr)
                            stage8(Xn + (size_t)(y0 + rr) * rowsz * 2,
                                   (char*)&Abuf[(y0 + rr - 2) & 7][0][0], 16896);
                    }
                }
                #pragma unroll
                for (int m = 0; m < 4; ++m)
                    #pragma unroll
                    for (int nf = 0; nf < 4; ++nf)
                        acc[m][nf] = MFMA16(ah[m], wh[nf], acc[m][nf]);
                #pragma unroll
                for (int m = 0; m < 4; ++m)
                    #pragma unroll
                    for (int nf = 0; nf < 4; ++nf)
                        acc[m][nf] = MFMA16(al[m], wh[nf], acc[m][nf]);
                #pragma unroll
                for (int m = 0; m < 4; ++m)
                    #pragma unroll
                    for (int nf = 0; nf < 4; ++nf)
                        acc[m][nf] = MFMA16(ah[m], wl_[nf], acc[m][nf]);
                KXBAR();
                p ^= 1;
            }
        }
    }

    // epilogue
    #pragma unroll
    for (int nf = 0; nf < 4; ++nf) {
        int co = co0 + nf * 16 + l15;
        float bv = bias[co];
        float s1 = 0.f, s2 = 0.f;
        size_t rowb = ((size_t)(b * 256 + co) * 128 + y) * 128 + xb;
        #pragma unroll
        for (int m = 0; m < 4; ++m) {
            size_t ob = rowb + m * 16 + lg * 4;
            f32x4 v = acc[m][nf];
            v.x += bv; v.y += bv; v.z += bv; v.w += bv;
            if (addbuf) {
                float4 rr = *(const float4*)(addbuf + ob);
                v.x += rr.x; v.y += rr.y; v.z += rr.z; v.w += rr.w;
            }
            *(f32x4*)(dst + ob) = v;
            if (tstats) {
                s1 += (v.x + v.y) + (v.z + v.w);
                s2 += (v.x * v.x + v.y * v.y) + (v.z * v.z + v.w * v.w);
            }
        }
        if (tstats) {
            for (int off = 32; off; off >>= 1) {
                s1 += __shfl_xor(s1, off);
                s2 += __shfl_xor(s2, off);
            }
            if (lane == 0) {
                int g = b * 16 + coq * 4 + nf;
                atomicAdd(&tstats[2 * g],     s1);
                atomicAdd(&tstats[2 * g + 1], s2);
            }
        }
    }
}

// ---------------------------------------------------------------------------
extern "C" void kernel_launch(void* const* d_in, const int* in_sizes, int n_in,
                              void* d_out, int out_size, void* d_ws, size_t ws_size,
                              hipStream_t stream)
{
    (void)in_sizes; (void)n_in; (void)out_size; (void)ws_size;
    const float* x        = (const float*)d_in[0];
    const float* norm1_w  = (const float*)d_in[1];
    const float* norm1_b  = (const float*)d_in[2];
    // d_in[3] (v_w), d_in[4] (v_b): dead code in the reference — skipped.
    const float* proj_w   = (const float*)d_in[5];
    const float* proj_b   = (const float*)d_in[6];
    const float* cn_w     = (const float*)d_in[7];
    const float* cn_b     = (const float*)d_in[8];
    const float* sim_a    = (const float*)d_in[9];
    const float* sim_b    = (const float*)d_in[10];
    const float* con_a    = (const float*)d_in[11];
    const float* rn1_w    = (const float*)d_in[12];
    const float* rn1_b    = (const float*)d_in[13];
    const float* rc1_w    = (const float*)d_in[14];
    const float* rc1_b    = (const float*)d_in[15];
    const float* rn2_w    = (const float*)d_in[16];
    const float* rn2_b    = (const float*)d_in[17];
    const float* rc2_w    = (const float*)d_in[18];
    const float* rc2_b    = (const float*)d_in[19];

    float* ws = (float*)d_ws;
    float* Bb    = ws;                      // t buffer [2,256,128,128] f32
    size_t o = NT;
    float* cf    = ws + o; o += 8192;
    float* dense = ws + o; o += 8192;
    float* simb  = ws + o; o += 1048576;
    float* biasp = ws + o; o += 512;
    // zeroed region: stats(256) | denp(256) | nump(8192) = 8704 floats
    float* stats = ws + o; o += 256;   // x-gn1@0[4], Bb-gn1@4[4], y-gn16@8[64], t-gn16@72[64]
    float* denp  = ws + o; o += 256;
    float* nump  = ws + o; o += 8192;
    u16* Pt  = (u16*)(ws + o);              // 2*8*16384*64 u16
    u16* Wp  = Pt + 16777216 + 2048;        // 2*8*256*64 u16
    u16* XtG = Wp + 524288 + 2048;          // 2*8*134*134*64 u16
    const size_t XTG_ELEMS = 2ull * 8 * 134 * 134 * 64;
    u16* Ws1 = XtG + XTG_ELEMS + 2048;      // 25*8*256*64 u16
    u16* Ws2 = Ws1 + 3276800 + 2048;
    float* C = (float*)d_out;               // y buffer aliases the output

    zero_small_k<<<34, 256, 0, stream>>>(stats);           // 34*256 == 8704
    zero_halo_k<<<2144, 256, 0, stream>>>(XtG);            // 16 planes * 134 rows
    prep_w_k<<<1600, 256, 0, stream>>>(rc1_w, Ws1);
    prep_w_k<<<1600, 256, 0, stream>>>(rc2_w, Ws2);

    // GN1(x) stats only; affine folded into cluster kernels
    reduce_stats_k<<<2048, 256, 0, stream>>>(x, stats + 0, CHW, 1024);
    centers_k<<<256, 256, 0, stream>>>(x, stats, norm1_w, norm1_b, cf);
    sim_part_k<<<256, 256, 0, stream>>>(x, stats, norm1_w, norm1_b, cf, simb,
                                        nump, denp, sim_a, sim_b);
    finalize_dense_k<<<32, 256, 0, stream>>>(nump, denp, cf, dense);
    dispatch_k<<<1024, 256, 0, stream>>>(simb, dense, Pt, stats);
    // GN-cn folded into W'; proj GEMM writes y (= x + ca*silu) + y-GN16 stats
    prep_wp_k<<<512, 256, 0, stream>>>(proj_w, proj_b, stats, cn_w, cn_b,
                                       Wp, biasp);
    proj_gemm_k<<<256, 512, 0, stream>>>(Pt, Wp, biasp, x, con_a, C, stats + 8);
    // ResnetBlock conv1 (t-stats fused into epilogue)
    prep_xtg_k<<<1024, 256, 0, stream>>>(C, stats + 8, rn1_w, rn1_b, XtG);
    conv_mfma_k<<<256, 512, 0, stream>>>(XtG, Ws1, rc1_b, nullptr, Bb, stats + 72);
    // ResnetBlock conv2 + residual
    prep_xtg_k<<<1024, 256, 0, stream>>>(Bb, stats + 72, rn2_w, rn2_b, XtG);
    conv_mfma_k<<<256, 512, 0, stream>>>(XtG, Ws2, rc2_b, C, C, nullptr);
}

// Round 7
// 692.464 us; speedup vs baseline: 7.4475x; 1.4809x over previous
//
#include <hip/hip_runtime.h>
#include <math.h>

// ---------------------------------------------------------------------------
// PD_Block, round 7: single-term f16 MFMA (error ~1e-3, analyzed safe) +
// coarse 2-phase prefetch schedule (40 barriers/conv, stage issued a full
// compute-window before its drain). Swizzle key (xs>>1)&3 -> 2-way LDS (free).
// ---------------------------------------------------------------------------

#define NT   8388608ull        // 2*256*128*128
#define CHW  4194304           // 256*128*128
#define HW   16384             // 128*128

typedef unsigned short u16;
typedef __attribute__((ext_vector_type(8))) _Float16 f16x8;
typedef __attribute__((ext_vector_type(4))) float f32x4;

#define MFMAH(a,b,c) __builtin_amdgcn_mfma_f32_16x16x32_f16(a,b,c,0,0,0)

__device__ __forceinline__ u16 f2h(float f) {
    union { _Float16 h; u16 u; } cv; cv.h = (_Float16)f; return cv.u;
}

__device__ __forceinline__ void gll16(const void* g, void* l) {
    __builtin_amdgcn_global_load_lds(
        (const __attribute__((address_space(1))) void*)g,
        (__attribute__((address_space(3))) void*)l, 16, 0, 0);
}
// linear global->LDS copy for 8-wave blocks; may overrun up to +1023 B into
// LDS slot slack; global overruns stay inside the allocated buffer.
__device__ __forceinline__ void stage8(const char* g, char* l, int bytes) {
    int lane = threadIdx.x & 63, wv = threadIdx.x >> 6;
    for (int off = wv << 10; off < bytes; off += 8192)
        gll16(g + off + lane * 16, l + off);
}

#define KXBAR()  do { \
    asm volatile("s_waitcnt vmcnt(0)" ::: "memory"); \
    __builtin_amdgcn_sched_barrier(0); \
    __builtin_amdgcn_s_barrier(); \
    __builtin_amdgcn_sched_barrier(0); } while (0)

// ---------------------------------------------------------------- zero utils
__global__ void zero_small_k(float* __restrict__ p) {
    p[blockIdx.x * 256 + threadIdx.x] = 0.f;     // grid*256 == region size
}
// zero XtG halo: rows ys{0,1,130,131} full; else cols xs{0,1,130,131}
__global__ __launch_bounds__(256) void zero_halo_k(u16* __restrict__ XtG) {
    int plane = blockIdx.x / 134, ys = blockIdx.x % 134;
    u16* row = XtG + ((size_t)plane * 134 + ys) * 32;
    // row stride between ys is 134*32; base above: plane*134*134*32 + ys*134*32
    row = XtG + ((size_t)plane * 134 + ys) * (134 * 32);
    uint4 z = make_uint4(0u, 0u, 0u, 0u);
    if (ys < 2 || (ys >= 130 && ys < 132)) {
        for (int i = threadIdx.x; i < 536; i += 256) ((uint4*)row)[i] = z;
    } else if (threadIdx.x < 16) {
        int xi = threadIdx.x >> 2;
        int xs = (xi < 2) ? xi : 128 + xi;       // 0,1,130,131
        ((uint4*)(row + xs * 32))[threadIdx.x & 3] = z;
    }
}

// ------------------------------------------------- generic group-stat reduce
__global__ __launch_bounds__(256) void reduce_stats_k(
    const float* __restrict__ src, float* __restrict__ stats,
    int elems_per_group, int blocks_per_group)
{
    int g   = blockIdx.x / blocks_per_group;
    int blk = blockIdx.x % blocks_per_group;
    int per_block = elems_per_group / blocks_per_group;
    const float* p = src + (size_t)g * elems_per_group + (size_t)blk * per_block;
    float s = 0.f, ss = 0.f;
    for (int i = threadIdx.x * 4; i < per_block; i += 256 * 4) {
        float4 v = *(const float4*)(p + i);
        s  += (v.x + v.y) + (v.z + v.w);
        ss += (v.x * v.x + v.y * v.y) + (v.z * v.z + v.w * v.w);
    }
    for (int off = 32; off; off >>= 1) {
        s  += __shfl_down(s, off);
        ss += __shfl_down(ss, off);
    }
    __shared__ float rs[4], rss[4];
    int lane = threadIdx.x & 63, wv = threadIdx.x >> 6;
    if (lane == 0) { rs[wv] = s; rss[wv] = ss; }
    __syncthreads();
    if (threadIdx.x == 0) {
        atomicAdd(&stats[2 * g],     rs[0] + rs[1] + rs[2] + rs[3]);
        atomicAdd(&stats[2 * g + 1], rss[0] + rss[1] + rss[2] + rss[3]);
    }
}

// --------------------------- cluster: centers (pool raw x, then GN1 affine)
__global__ __launch_bounds__(256) void centers_k(
    const float* __restrict__ x, const float* __restrict__ stats,
    const float* __restrict__ n1w, const float* __restrict__ n1b,
    float* __restrict__ cf)
{
    int sm = blockIdx.x;
    int m = sm & 3, s = sm >> 2;
    int f3 = s & 1, f2 = (s >> 1) & 1, head = (s >> 2) & 7, bb = s >> 5;
    int mh = m & 1, mw = m >> 1;
    int c = threadIdx.x & 31, grp = threadIdx.x >> 5;
    const float* base = x + ((size_t)(bb * 256 + head * 32 + c) * 128
                             + f2 * 64 + mw * 32) * 128 + f3 * 64 + mh * 32;
    float sum = 0.f;
    for (int r = grp; r < 32; r += 8) {
        const float* row = base + r * 128;
        #pragma unroll
        for (int q = 0; q < 8; q++) {
            float4 v = *(const float4*)(row + q * 4);
            sum += (v.x + v.y) + (v.z + v.w);
        }
    }
    __shared__ float red[8][32];
    red[grp][c] = sum;
    __syncthreads();
    if (grp == 0) {
        float t = 0.f;
        #pragma unroll
        for (int k = 0; k < 8; k++) t += red[k][c];
        float mean = stats[2 * bb] * (1.f / CHW);
        float var  = stats[2 * bb + 1] * (1.f / CHW) - mean * mean;
        float rsv  = rsqrtf(var + 1e-5f);
        int ch = head * 32 + c;
        float sc = rsv * n1w[ch];
        float sh = n1b[ch] - mean * sc;
        cf[(size_t)sm * 32 + c] = (t * (1.f / 1024.f)) * sc + sh;
    }
}

// --------------- cluster: sim + partial num/den (4 blocks per s, atomics)
__global__ __launch_bounds__(256) void sim_part_k(
    const float* __restrict__ x, const float* __restrict__ stats,
    const float* __restrict__ n1w, const float* __restrict__ n1b,
    const float* __restrict__ cf, float* __restrict__ simb,
    float* __restrict__ nump, float* __restrict__ denp,
    const float* __restrict__ alphap, const float* __restrict__ betap)
{
    int sq = blockIdx.x;
    int q = sq & 3, s = sq >> 2;
    int f3 = s & 1, f2 = (s >> 1) & 1, head = (s >> 2) & 7, bb = s >> 5;
    int tid = threadIdx.x;
    float alpha = alphap[0], beta = betap[0];

    __shared__ float cfr[4][32], cfn[4][32], invn[4], scs[32], shs[32];
    if (tid < 128) {
        int m = tid >> 5, c = tid & 31;
        cfr[m][c] = cf[(size_t)(s * 4 + m) * 32 + c];
    }
    if (tid >= 128 && tid < 160) {
        int c = tid - 128;
        float mean = stats[2 * bb] * (1.f / CHW);
        float var  = stats[2 * bb + 1] * (1.f / CHW) - mean * mean;
        float rsv  = rsqrtf(var + 1e-5f);
        int ch = head * 32 + c;
        float sc = rsv * n1w[ch];
        scs[c] = sc;
        shs[c] = n1b[ch] - mean * sc;
    }
    __syncthreads();
    if (tid < 4) {
        float n = 0.f;
        for (int c = 0; c < 32; c++) n += cfr[tid][c] * cfr[tid][c];
        invn[tid] = 1.f / fmaxf(sqrtf(n), 1e-12f);
    }
    __syncthreads();
    if (tid < 128) {
        int m = tid >> 5, c = tid & 31;
        cfn[m][c] = cfr[m][c] * invn[m];
    }
    __syncthreads();

    const float* xbase = x + ((size_t)(bb * 256 + head * 32) * 128 + f2 * 64) * 128
                           + f3 * 64;
    float num[4][32];
    float den[4] = {0.f, 0.f, 0.f, 0.f};
    #pragma unroll
    for (int m = 0; m < 4; m++)
        #pragma unroll
        for (int c = 0; c < 32; c++) num[m][c] = 0.f;

    for (int n0 = 0; n0 < 1024; n0 += 256) {
        int n = q * 1024 + n0 + tid;
        int w = n >> 6, h = n & 63;
        const float* px = xbase + w * 128 + h;
        float f[32]; float ss = 0.f;
        #pragma unroll
        for (int c = 0; c < 32; c++) {
            f[c] = px[(size_t)c * HW] * scs[c] + shs[c];
            ss += f[c] * f[c];
        }
        float inv = 1.f / fmaxf(sqrtf(ss), 1e-12f);
        #pragma unroll
        for (int m = 0; m < 4; m++) {
            float dot = 0.f;
            #pragma unroll
            for (int c = 0; c < 32; c++) dot += cfn[m][c] * f[c];
            float z = beta + alpha * dot * inv;
            float sv = 1.f / (1.f + expf(-z));
            simb[((size_t)s * 4 + m) * 4096 + n] = sv;
            den[m] += sv;
            #pragma unroll
            for (int c = 0; c < 32; c++) num[m][c] = fmaf(sv, f[c], num[m][c]);
        }
    }

    __shared__ float rnum[4][128];
    __shared__ float rden[4][4];
    int lane = tid & 63, wv = tid >> 6;
    #pragma unroll
    for (int m = 0; m < 4; m++) {
        #pragma unroll
        for (int c = 0; c < 32; c++) {
            float v = num[m][c];
            for (int off = 32; off; off >>= 1) v += __shfl_xor(v, off);
            if (lane == 0) rnum[wv][m * 32 + c] = v;
        }
        float d = den[m];
        for (int off = 32; off; off >>= 1) d += __shfl_xor(d, off);
        if (lane == 0) rden[wv][m] = d;
    }
    __syncthreads();
    if (tid < 4)
        atomicAdd(&denp[s * 4 + tid],
                  rden[0][tid] + rden[1][tid] + rden[2][tid] + rden[3][tid]);
    if (tid < 128) {
        int m = tid >> 5, c = tid & 31;
        float nsum = rnum[0][tid] + rnum[1][tid] + rnum[2][tid] + rnum[3][tid];
        atomicAdd(&nump[(size_t)(s * 4 + m) * 32 + c], nsum);
    }
}

// ------------------------------------------------------- finalize dense_out
__global__ void finalize_dense_k(const float* __restrict__ nump,
                                 const float* __restrict__ denp,
                                 const float* __restrict__ cf,
                                 float* __restrict__ dense)
{
    int i = blockIdx.x * 256 + threadIdx.x;   // 32 blocks * 256 = 8192
    dense[i] = (nump[i] + cf[i]) / (denp[i >> 5] + 1.0f);
}

// ------- cluster dispatch: write Pt f16 swizzled + fused Bb GN1 stats
// Pt[b][cib=head][px(16384)][32k], 16B units at u' = u ^ ((px>>1)&3)
__global__ __launch_bounds__(256) void dispatch_k(
    const float* __restrict__ simb, const float* __restrict__ dense,
    u16* __restrict__ Pt, float* __restrict__ stats)
{
    int s = blockIdx.x >> 4, chunk = blockIdx.x & 15;
    int tid = threadIdx.x;
    __shared__ float dl[4][32];
    if (tid < 128) {
        int m = tid >> 5, c = tid & 31;
        dl[m][c] = dense[(size_t)(s * 4 + m) * 32 + c];
    }
    __syncthreads();
    int n = chunk * 256 + tid;
    int w = n >> 6, h = n & 63;
    int f3 = s & 1, f2 = (s >> 1) & 1, head = (s >> 2) & 7, bb = s >> 5;
    float sv[4];
    #pragma unroll
    for (int m = 0; m < 4; m++) sv[m] = simb[((size_t)s * 4 + m) * 4096 + n];
    int px = (f2 * 64 + w) * 128 + (f3 * 64 + h);
    u16 vals[32];
    float s1 = 0.f, s2 = 0.f;
    #pragma unroll
    for (int c = 0; c < 32; c++) {
        float v = dl[0][c] * sv[0] + dl[1][c] * sv[1]
                + dl[2][c] * sv[2] + dl[3][c] * sv[3];
        s1 += v; s2 += v * v;
        vals[c] = f2h(v);
    }
    u16* base = Pt + (((size_t)bb * 8 + head) * 16384 + px) * 32;
    int key = (px >> 1) & 3;
    #pragma unroll
    for (int u = 0; u < 4; ++u) {
        uint4 v;
        v.x = (unsigned)vals[u*8+0] | ((unsigned)vals[u*8+1] << 16);
        v.y = (unsigned)vals[u*8+2] | ((unsigned)vals[u*8+3] << 16);
        v.z = (unsigned)vals[u*8+4] | ((unsigned)vals[u*8+5] << 16);
        v.w = (unsigned)vals[u*8+6] | ((unsigned)vals[u*8+7] << 16);
        *(uint4*)(base + (u ^ key) * 8) = v;
    }
    for (int off = 32; off; off >>= 1) {
        s1 += __shfl_xor(s1, off);
        s2 += __shfl_xor(s2, off);
    }
    __shared__ float r1[4], r2[4];
    int lane = tid & 63, wv = tid >> 6;
    if (lane == 0) { r1[wv] = s1; r2[wv] = s2; }
    __syncthreads();
    if (tid == 0) {
        atomicAdd(&stats[4 + 2 * bb], r1[0] + r1[1] + r1[2] + r1[3]);
        atomicAdd(&stats[5 + 2 * bb], r2[0] + r2[1] + r2[2] + r2[3]);
    }
}

// ------------- prep proj weights: W'[b][cib][co][32k] f16 = w*sc, bias'
__global__ __launch_bounds__(256) void prep_wp_k(
    const float* __restrict__ w, const float* __restrict__ pb,
    const float* __restrict__ stats, const float* __restrict__ cnw,
    const float* __restrict__ cnb, u16* __restrict__ Wp,
    float* __restrict__ biasp)
{
    int b = blockIdx.x >> 8, co = blockIdx.x & 255;
    int ci = threadIdx.x;
    float mean = stats[4 + 2 * b] * (1.f / CHW);
    float var  = stats[5 + 2 * b] * (1.f / CHW) - mean * mean;
    float rsv  = rsqrtf(var + 1e-5f);
    float sc = rsv * cnw[ci];
    float sh = cnb[ci] - mean * sc;
    float wv = w[(size_t)co * 256 + ci];
    __shared__ u16 buf[256];
    __shared__ float red[256];
    buf[ci] = f2h(wv * sc);          // logical [cib=ci>>5][k=ci&31]
    red[ci] = wv * sh;
    __syncthreads();
    if (ci < 32) {
        int cb = ci >> 2, up = ci & 3;
        int u = up ^ ((co >> 1) & 3);
        const u16* o = &buf[cb * 32 + u * 8];
        uint4 v;
        v.x = (unsigned)o[0] | ((unsigned)o[1] << 16);
        v.y = (unsigned)o[2] | ((unsigned)o[3] << 16);
        v.z = (unsigned)o[4] | ((unsigned)o[5] << 16);
        v.w = (unsigned)o[6] | ((unsigned)o[7] << 16);
        *(uint4*)(Wp + (((size_t)b * 8 + cb) * 256 + co) * 32 + up * 8) = v;
    }
    for (int st = 128; st; st >>= 1) {
        if (ci < st) red[ci] += red[ci + st];
        __syncthreads();
    }
    if (ci == 0) biasp[b * 256 + co] = pb[co] + red[0];
}

// ----------- proj MFMA GEMM (f16): y = x + ca*silu(Pt W' + b'), + y stats
// grid 256 = (b, 128px-tile); 8 waves = (pxH 2, coQ 4); wave 64px x 64co.
__global__ __launch_bounds__(512, 2) void proj_gemm_k(
    const u16* __restrict__ Pt, const u16* __restrict__ Wp,
    const float* __restrict__ biasp, const float* __restrict__ xin,
    const float* __restrict__ cap, float* __restrict__ dst,
    float* __restrict__ ystats)
{
    __shared__ u16 Apt[2][128][32];    // 16 KB
    __shared__ u16 Wl[2][256][32];     // 32 KB
    int bid = blockIdx.x;
    int b = bid >> 7, t = bid & 127;
    int px0 = t * 128;
    int tid = threadIdx.x, lane = tid & 63, wv = tid >> 6;
    int pxH = wv & 1, coQ = wv >> 1;
    int l15 = lane & 15, lg = lane >> 4;
    float ca = cap[0];
    const u16* Ptb = Pt + (size_t)b * 8 * 16384 * 32;
    const u16* Wpb = Wp + (size_t)b * 8 * 256 * 32;

    f32x4 acc[4][4];
    #pragma unroll
    for (int m = 0; m < 4; ++m)
        #pragma unroll
        for (int nf = 0; nf < 4; ++nf)
            acc[m][nf] = (f32x4){0.f, 0.f, 0.f, 0.f};

    stage8((const char*)(Ptb + (size_t)px0 * 32), (char*)&Apt[0][0][0], 8192);
    stage8((const char*)(Wpb), (char*)&Wl[0][0][0], 16384);
    KXBAR();

    for (int cib = 0; cib < 8; ++cib) {
        int cur = cib & 1;
        if (cib < 7) {
            stage8((const char*)(Ptb + ((size_t)(cib + 1) * 16384 + px0) * 32),
                   (char*)&Apt[cur ^ 1][0][0], 8192);
            stage8((const char*)(Wpb + (size_t)(cib + 1) * 256 * 32),
                   (char*)&Wl[cur ^ 1][0][0], 16384);
        }
        f16x8 ah[4], wh[4];
        #pragma unroll
        for (int m = 0; m < 4; ++m) {
            int pxl = pxH * 64 + m * 16 + l15;
            int ph = lg ^ ((pxl >> 1) & 3);
            ah[m] = *(const f16x8*)(&Apt[cur][pxl][0] + ph * 8);
        }
        #pragma unroll
        for (int nf = 0; nf < 4; ++nf) {
            int cr = coQ * 64 + nf * 16 + l15;
            int ph = lg ^ ((cr >> 1) & 3);
            wh[nf] = *(const f16x8*)(&Wl[cur][cr][0] + ph * 8);
        }
        #pragma unroll
        for (int m = 0; m < 4; ++m)
            #pragma unroll
            for (int nf = 0; nf < 4; ++nf)
                acc[m][nf] = MFMAH(ah[m], wh[nf], acc[m][nf]);
        KXBAR();
    }

    #pragma unroll
    for (int nf = 0; nf < 4; ++nf) {
        int co = coQ * 64 + nf * 16 + l15;
        float bv = biasp[b * 256 + co];
        float s1 = 0.f, s2 = 0.f;
        #pragma unroll
        for (int m = 0; m < 4; ++m) {
            int px = px0 + pxH * 64 + m * 16 + lg * 4;
            size_t ga = ((size_t)(b * 256 + co)) * HW + px;
            f32x4 v = acc[m][nf];
            float o[4] = { v.x + bv, v.y + bv, v.z + bv, v.w + bv };
            float4 xr = *(const float4*)(xin + ga);
            float xa[4] = { xr.x, xr.y, xr.z, xr.w };
            f32x4 yv;
            #pragma unroll
            for (int k = 0; k < 4; ++k) {
                float sl = o[k] / (1.f + expf(-o[k]));
                float yy = xa[k] + ca * sl;
                ((float*)&yv)[k] = yy;
                s1 += yy; s2 += yy * yy;
            }
            *(f32x4*)(dst + ga) = yv;
        }
        for (int off = 32; off; off >>= 1) {
            s1 += __shfl_xor(s1, off);
            s2 += __shfl_xor(s2, off);
        }
        if (lane == 0) {
            int g = b * 16 + coQ * 4 + nf;
            atomicAdd(&ystats[2 * g],     s1);
            atomicAdd(&ystats[2 * g + 1], s2);
        }
    }
}

// --------------------- prep: conv weights f16 [step=cib*5+ky][coq][kx][64co][32k]
// 16B unit at phys up, logical u = up ^ ((co>>1)&3). grid 800 x 256.
__global__ __launch_bounds__(256) void prep_w_k(
    const float* __restrict__ w, u16* __restrict__ Ws)
{
    int idx = blockIdx.x * 256 + threadIdx.x;    // 204800 units
    int up = idx & 3; int t = idx >> 2;
    int co = t & 255; t >>= 8;
    int kx = t % 5; t /= 5;
    int ky = t % 5; t /= 5;
    int cib = t;
    int u = up ^ ((co >> 1) & 3);
    int ci0 = cib * 32 + u * 8;
    u16 vals[8];
    #pragma unroll
    for (int j = 0; j < 8; ++j)
        vals[j] = f2h(w[(((size_t)co * 256 + (ci0 + j)) * 5 + ky) * 5 + kx]);
    uint4 v;
    v.x = (unsigned)vals[0] | ((unsigned)vals[1] << 16);
    v.y = (unsigned)vals[2] | ((unsigned)vals[3] << 16);
    v.z = (unsigned)vals[4] | ((unsigned)vals[5] << 16);
    v.w = (unsigned)vals[6] | ((unsigned)vals[7] << 16);
    size_t dst = ((((size_t)(cib * 5 + ky) * 4 + (co >> 6)) * 5 + kx) * 64
                  + (co & 63)) * 32 + up * 8;
    *(uint4*)(Ws + dst) = v;
}

// -------------------- prep: GN16 + silu + f16 + transpose -> XtG (padded)
// XtG[b][cib][ys134][xs134][32k], unit at u' = u ^ ((xs>>1)&3). grid 1024.
__global__ __launch_bounds__(256) void prep_xtg_k(
    const float* __restrict__ src, const float* __restrict__ stats,
    const float* __restrict__ gw, const float* __restrict__ gb,
    u16* __restrict__ XtG)
{
    int bb = blockIdx.x >> 9, rem = blockIdx.x & 511;
    int yy = rem >> 2, xc = rem & 3;
    __shared__ float tile[256][33];
    int tid = threadIdx.x;
    int xx = tid & 31, cg = tid >> 5;          // cg == cib
    int x0 = xc * 32;
    for (int i = tid; i < 8192; i += 256) {
        int c = i >> 5, xl = i & 31;
        tile[c][xl] = src[((size_t)(bb * 256 + c) * 128 + yy) * 128 + x0 + xl];
    }
    __syncthreads();
    int x = x0 + xx;
    u16 vals[32];
    #pragma unroll
    for (int ci = 0; ci < 32; ++ci) {
        int c = cg * 32 + ci;
        int g = bb * 16 + (c >> 4);
        float mean = stats[2 * g] * (1.f / 262144.f);
        float var  = stats[2 * g + 1] * (1.f / 262144.f) - mean * mean;
        float rsv  = rsqrtf(var + 1e-5f);
        float v = (tile[c][xx] - mean) * rsv * gw[c] + gb[c];
        v = v / (1.f + expf(-v));
        vals[ci] = f2h(v);
    }
    int xs = x + 2;
    int key = (xs >> 1) & 3;
    u16* base = XtG + ((((size_t)bb * 8 + cg) * 134 + (yy + 2)) * 134 + xs) * 32;
    #pragma unroll
    for (int u = 0; u < 4; ++u) {
        uint4 v;
        v.x = (unsigned)vals[u*8+0] | ((unsigned)vals[u*8+1] << 16);
        v.y = (unsigned)vals[u*8+2] | ((unsigned)vals[u*8+3] << 16);
        v.z = (unsigned)vals[u*8+4] | ((unsigned)vals[u*8+5] << 16);
        v.w = (unsigned)vals[u*8+6] | ((unsigned)vals[u*8+7] << 16);
        *(uint4*)(base + (u ^ key) * 8) = v;
    }
}

// --------------------------------------- conv5x5 f16 MFMA, 2-phase schedule
// 8 waves (2/SIMD): wave = row r(0..3) x x-half(64px) x 64co. 40 steps
// (cib,ky); per step: issue next W(20.5KB)+A-row stages, compute 5kx, KXBAR.
__global__ __launch_bounds__(512, 1) void conv_mfma_k(
    const u16* __restrict__ XtG, const u16* __restrict__ Ws,
    const float* __restrict__ bias, const float* __restrict__ addbuf,
    float* __restrict__ dst, float* __restrict__ tstats)
{
    __shared__ u16 Abuf[8][144][32];   // 73,728 B (slot 9216: 8448 + slack)
    __shared__ u16 Wlds[2][10240];     // 40,960 B

    int bid = blockIdx.x;
    int xcd = bid & 7, j = bid >> 3;
    int coq = xcd >> 1, b = xcd & 1;   // each XCD one (coq,b): W-set 0.8MB < L2
    int y0 = j * 4, co0 = coq * 64;
    int tid = threadIdx.x, lane = tid & 63, wv = tid >> 6;
    int r = wv >> 1, xh = wv & 1;
    int l15 = lane & 15, lg = lane >> 4;
    int y = y0 + r, xb = xh * 64;

    const size_t plane = (size_t)134 * 134 * 32;
    const size_t rowsz = (size_t)134 * 32;
    const u16* Xb = XtG + (size_t)b * 8 * plane;

    f32x4 acc[4][4];
    #pragma unroll
    for (int m = 0; m < 4; ++m)
        #pragma unroll
        for (int nf = 0; nf < 4; ++nf)
            acc[m][nf] = (f32x4){0.f, 0.f, 0.f, 0.f};

    // prologue: A rows ys=y0..y0+3 (cib0), W step0
    #pragma unroll
    for (int rr = 0; rr < 4; ++rr)
        stage8((const char*)(Xb + (size_t)(y0 + rr) * rowsz),
               (char*)&Abuf[(y0 + rr) & 7][0][0], 8448);
    stage8((const char*)(Ws + (size_t)coq * 10240), (char*)&Wlds[0][0], 20480);
    KXBAR();

    int s = 0;
    for (int cib = 0; cib < 8; ++cib) {
        const u16* Xc = Xb + (size_t)cib * plane;
        for (int ky = 0; ky < 5; ++ky) {
            int step = cib * 5 + ky;
            // issue next-step stages (drain comes after this step's compute)
            if (step < 39)
                stage8((const char*)(Ws + (size_t)((step + 1) * 4 + coq) * 10240),
                       (char*)&Wlds[s ^ 1][0], 20480);
            if (ky < 4) {
                int ys = y0 + ky + 4;
                stage8((const char*)(Xc + (size_t)ys * rowsz),
                       (char*)&Abuf[ys & 7][0][0], 8448);
            } else if (cib < 7) {
                const u16* Xn = Xc + plane;
                #pragma unroll
                for (int rr = 0; rr < 4; ++rr)
                    stage8((const char*)(Xn + (size_t)(y0 + rr) * rowsz),
                           (char*)&Abuf[(y0 + rr) & 7][0][0], 8448);
            }
            // compute 5 kx from Abuf slot (y+ky)&7 and Wlds[s]
            const u16* Ab = &Abuf[(y + ky) & 7][0][0];
            const u16* Wb = &Wlds[s][0];
            #pragma unroll
            for (int kx = 0; kx < 5; ++kx) {
                const u16* Wk = Wb + kx * 2048;
                f16x8 wh[4], ah[4];
                #pragma unroll
                for (int nf = 0; nf < 4; ++nf) {
                    int cr = nf * 16 + l15;
                    int ph = lg ^ ((cr >> 1) & 3);
                    wh[nf] = *(const f16x8*)(Wk + cr * 32 + ph * 8);
                }
                #pragma unroll
                for (int m = 0; m < 4; ++m) {
                    int xs = xb + m * 16 + l15 + kx;
                    int ph = lg ^ ((xs >> 1) & 3);
                    ah[m] = *(const f16x8*)(Ab + xs * 32 + ph * 8);
                }
                #pragma unroll
                for (int m = 0; m < 4; ++m)
                    #pragma unroll
                    for (int nf = 0; nf < 4; ++nf)
                        acc[m][nf] = MFMAH(ah[m], wh[nf], acc[m][nf]);
            }
            KXBAR();
            s ^= 1;
        }
    }

    // epilogue: px = xb + m*16 + lg*4 + reg ; co = co0 + nf*16 + l15
    #pragma unroll
    for (int nf = 0; nf < 4; ++nf) {
        int co = co0 + nf * 16 + l15;
        float bv = bias[co];
        float s1 = 0.f, s2 = 0.f;
        size_t rowb = ((size_t)(b * 256 + co) * 128 + y) * 128 + xb;
        #pragma unroll
        for (int m = 0; m < 4; ++m) {
            size_t ob = rowb + m * 16 + lg * 4;
            f32x4 v = acc[m][nf];
            v.x += bv; v.y += bv; v.z += bv; v.w += bv;
            if (addbuf) {
                float4 rr = *(const float4*)(addbuf + ob);
                v.x += rr.x; v.y += rr.y; v.z += rr.z; v.w += rr.w;
            }
            *(f32x4*)(dst + ob) = v;
            if (tstats) {
                s1 += (v.x + v.y) + (v.z + v.w);
                s2 += (v.x * v.x + v.y * v.y) + (v.z * v.z + v.w * v.w);
            }
        }
        if (tstats) {
            for (int off = 32; off; off >>= 1) {
                s1 += __shfl_xor(s1, off);
                s2 += __shfl_xor(s2, off);
            }
            if (lane == 0) {
                int g = b * 16 + coq * 4 + nf;
                atomicAdd(&tstats[2 * g],     s1);
                atomicAdd(&tstats[2 * g + 1], s2);
            }
        }
    }
}

// ---------------------------------------------------------------------------
extern "C" void kernel_launch(void* const* d_in, const int* in_sizes, int n_in,
                              void* d_out, int out_size, void* d_ws, size_t ws_size,
                              hipStream_t stream)
{
    (void)in_sizes; (void)n_in; (void)out_size; (void)ws_size;
    const float* x        = (const float*)d_in[0];
    const float* norm1_w  = (const float*)d_in[1];
    const float* norm1_b  = (const float*)d_in[2];
    // d_in[3] (v_w), d_in[4] (v_b): dead code in the reference — skipped.
    const float* proj_w   = (const float*)d_in[5];
    const float* proj_b   = (const float*)d_in[6];
    const float* cn_w     = (const float*)d_in[7];
    const float* cn_b     = (const float*)d_in[8];
    const float* sim_a    = (const float*)d_in[9];
    const float* sim_b    = (const float*)d_in[10];
    const float* con_a    = (const float*)d_in[11];
    const float* rn1_w    = (const float*)d_in[12];
    const float* rn1_b    = (const float*)d_in[13];
    const float* rc1_w    = (const float*)d_in[14];
    const float* rc1_b    = (const float*)d_in[15];
    const float* rn2_w    = (const float*)d_in[16];
    const float* rn2_b    = (const float*)d_in[17];
    const float* rc2_w    = (const float*)d_in[18];
    const float* rc2_b    = (const float*)d_in[19];

    float* ws = (float*)d_ws;
    float* Bb    = ws;                      // t buffer [2,256,128,128] f32
    size_t o = NT;
    float* cf    = ws + o; o += 8192;
    float* dense = ws + o; o += 8192;
    float* simb  = ws + o; o += 1048576;
    float* biasp = ws + o; o += 512;
    // zeroed region: stats(256) | denp(256) | nump(8192) = 8704 floats
    float* stats = ws + o; o += 256;   // x-gn1@0, Bb-gn1@4, y-gn16@8, t-gn16@72
    float* denp  = ws + o; o += 256;
    float* nump  = ws + o; o += 8192;
    u16* Pt  = (u16*)(ws + o);              // 2*8*16384*32 = 8,388,608 u16
    u16* Wp  = Pt + 8388608 + 2048;         // 131,072 u16
    u16* XtG = Wp + 131072 + 2048;          // 2*8*134*134*32 = 9,193,472 u16
    u16* Ws1 = XtG + 9193472 + 2048;        // 1,638,400 u16
    u16* Ws2 = Ws1 + 1638400 + 2048;
    float* C = (float*)d_out;               // y buffer aliases the output

    zero_small_k<<<34, 256, 0, stream>>>(stats);           // 34*256 == 8704
    zero_halo_k<<<2144, 256, 0, stream>>>(XtG);            // 16 planes * 134
    prep_w_k<<<800, 256, 0, stream>>>(rc1_w, Ws1);
    prep_w_k<<<800, 256, 0, stream>>>(rc2_w, Ws2);

    // GN1(x) stats only; affine folded into cluster kernels
    reduce_stats_k<<<2048, 256, 0, stream>>>(x, stats + 0, CHW, 1024);
    centers_k<<<256, 256, 0, stream>>>(x, stats, norm1_w, norm1_b, cf);
    sim_part_k<<<256, 256, 0, stream>>>(x, stats, norm1_w, norm1_b, cf, simb,
                                        nump, denp, sim_a, sim_b);
    finalize_dense_k<<<32, 256, 0, stream>>>(nump, denp, cf, dense);
    dispatch_k<<<1024, 256, 0, stream>>>(simb, dense, Pt, stats);
    // GN-cn folded into W'; proj GEMM writes y + y-GN16 stats
    prep_wp_k<<<512, 256, 0, stream>>>(proj_w, proj_b, stats, cn_w, cn_b,
                                       Wp, biasp);
    proj_gemm_k<<<256, 512, 0, stream>>>(Pt, Wp, biasp, x, con_a, C, stats + 8);
    // ResnetBlock conv1 (t-stats fused into epilogue)
    prep_xtg_k<<<1024, 256, 0, stream>>>(C, stats + 8, rn1_w, rn1_b, XtG);
    conv_mfma_k<<<256, 512, 0, stream>>>(XtG, Ws1, rc1_b, nullptr, Bb, stats + 72);
    // ResnetBlock conv2 + residual
    prep_xtg_k<<<1024, 256, 0, stream>>>(Bb, stats + 72, rn2_w, rn2_b, XtG);
    conv_mfma_k<<<256, 512, 0, stream>>>(XtG, Ws2, rc2_b, C, C, nullptr);
}